// Round 8
// baseline (438.451 us; speedup 1.0000x reference)
//
#include <hip/hip_runtime.h>
#include <hip/hip_fp16.h>

#define N_NODES 50000
#define N_EDGES 1600000
#define H 64
#define IN_CH 7
#define EDIM 4
#define G_GRAPHS 256
#define FC 128
#define NC 2
#define SLOPE 0.2f
#define BSH 5                           // bucket shift: 32 nodes per bucket
#define BNODES 32
#define NBUCK ((N_NODES + BNODES - 1) / BNODES)    // 1563
#define CAP 1536                        // LDS pair slots per bucket (mean 1024, sigma 32)
#define EPB1 8192                       // edges per front hist block
#define NB1 ((N_EDGES + EPB1 - 1) / EPB1)          // 196
#define PAIR_BLOCKS ((N_NODES * 32 + 255) / 256)   // 6250

typedef _Float16 h2v __attribute__((ext_vector_type(2)));

__device__ __forceinline__ float fdot2f(h2v a, h2v b, float c) {
#if defined(__has_builtin) && __has_builtin(__builtin_amdgcn_fdot2)
    return __builtin_amdgcn_fdot2(a, b, c, false);
#else
    return c + (float)a[0] * (float)b[0] + (float)a[1] * (float)b[1];
#endif
}

// per-edge GATv2 score, packed fp16
__device__ __forceinline__ float gat_score(int4 ent,
        const __half2* __restrict__ xlh, const __half2* __restrict__ xrh,
        const __half2* __restrict__ weh, const __half2* __restrict__ atth) {
    __half2 ea01 = *reinterpret_cast<__half2*>(&ent.y);
    __half2 ea23 = *reinterpret_cast<__half2*>(&ent.z);
    __half2 e0 = __half2half2(__low2half(ea01));
    __half2 e1 = __half2half2(__high2half(ea01));
    __half2 e2 = __half2half2(__low2half(ea23));
    __half2 e3 = __half2half2(__high2half(ea23));
    const h2v sl = { (_Float16)SLOPE, (_Float16)SLOPE };
    const int4* xa = (const int4*)(xlh + (size_t)ent.x * 32);
    const int4* xb = (const int4*)(xrh + (size_t)ent.w * 32);
    float acc0 = 0.f, acc1 = 0.f;
#pragma unroll
    for (int k = 0; k < 8; ++k) {
        int4 va = xa[k];
        int4 vb = xb[k];
        const __half2* ha = reinterpret_cast<const __half2*>(&va);
        const __half2* hc = reinterpret_cast<const __half2*>(&vb);
#pragma unroll
        for (int j = 0; j < 4; ++j) {
            int c = k * 4 + j;                     // uniform -> scalar weight loads
            __half2 v2 = __hadd2(ha[j], hc[j]);
            v2 = __hfma2(e0, weh[c * 4 + 0], v2);
            v2 = __hfma2(e1, weh[c * 4 + 1], v2);
            v2 = __hfma2(e2, weh[c * 4 + 2], v2);
            v2 = __hfma2(e3, weh[c * 4 + 3], v2);
            h2v vv = *reinterpret_cast<h2v*>(&v2);
            h2v Lv = __builtin_elementwise_max(vv, sl * vv);   // v_pk_max_f16 leaky-relu
            __half2 av = atth[c];
            if (j & 1)
                acc1 = fdot2f(Lv, *reinterpret_cast<h2v*>(&av), acc1);
            else
                acc0 = fdot2f(Lv, *reinterpret_cast<h2v*>(&av), acc0);
        }
    }
    return acc0 + acc1;
}

// ---------------- fused front-end: coarse histogram+rank (LDS atomics) + proj0 + prep ----------------
__global__ __launch_bounds__(256) void front_kernel(
        const int* __restrict__ dst, int* __restrict__ rank1, int* __restrict__ bhist,
        const float* __restrict__ xin,
        const float* __restrict__ Wl0, const float* __restrict__ bl0,
        const float* __restrict__ Wr0, const float* __restrict__ br0,
        __half2* __restrict__ xlh, __half2* __restrict__ xrh,
        const float* __restrict__ We0, const float* __restrict__ We1,
        const float* __restrict__ Wl1, const float* __restrict__ bl1,
        const float* __restrict__ Wr1, const float* __restrict__ br1,
        __half2* __restrict__ weh0, __half2* __restrict__ weh1,
        __half2* __restrict__ wt, float* __restrict__ bb,
        const float* __restrict__ att0, const float* __restrict__ att1,
        __half2* __restrict__ atth0, __half2* __restrict__ atth1) {
    __shared__ int hist[NBUCK];
    int b = blockIdx.x;
    int t = threadIdx.x;
    if (b < NB1) {
        for (int i = t; i < NBUCK; i += 256) hist[i] = 0;
        __syncthreads();
#pragma unroll
        for (int i = 0; i < EPB1 / 256; ++i) {
            int e = b * EPB1 + i * 256 + t;
            if (e < N_EDGES) {
                int k = dst[e] >> BSH;
                rank1[e] = atomicAdd(&hist[k], 1);
            }
        }
        __syncthreads();
        for (int i = t; i < NBUCK; i += 256) bhist[b * NBUCK + i] = hist[i];
    } else if (b < NB1 + PAIR_BLOCKS) {
        int idx = (b - NB1) * 256 + t;
        if (idx < N_NODES * 32) {
            int n = idx >> 5;
            int c = idx & 31;
            const float* xi = xin + n * IN_CH;
            float2 bl2 = ((const float2*)bl0)[c];
            float2 br2 = ((const float2*)br0)[c];
            float al0 = bl2.x, al1 = bl2.y, ar0 = br2.x, ar1 = br2.y;
#pragma unroll
            for (int k = 0; k < IN_CH; ++k) {
                float xv = xi[k];
                float2 wl2 = ((const float2*)(Wl0 + k * H))[c];
                float2 wr2 = ((const float2*)(Wr0 + k * H))[c];
                al0 += xv * wl2.x; al1 += xv * wl2.y;
                ar0 += xv * wr2.x; ar1 += xv * wr2.y;
            }
            xlh[idx] = __floats2half2_rn(al0, al1);
            xrh[idx] = __floats2half2_rn(ar0, ar1);
        }
    } else {
        if (t < 32) {
            for (int k = 0; k < 4; ++k)
                weh0[t * 4 + k] = __floats2half2_rn(We0[k * H + 2 * t], We0[k * H + 2 * t + 1]);
        } else if (t < 64) {
            int c = t - 32;
            for (int k = 0; k < 4; ++k)
                weh1[c * 4 + k] = __floats2half2_rn(We1[k * H + 2 * c], We1[k * H + 2 * c + 1]);
        }
        if (t < 128) {
            const float* W = (t < 64) ? Wl1 : Wr1;
            int c = t & 63;
            for (int kk = 0; kk < 32; ++kk)
                wt[t * 32 + kk] = __floats2half2_rn(W[(2 * kk) * H + c], W[(2 * kk + 1) * H + c]);
            bb[t] = (t < 64) ? bl1[c] : br1[c];
        } else if (t < 160) {
            int c = t - 128;
            atth0[c] = __floats2half2_rn(att0[2 * c], att0[2 * c + 1]);
            atth1[c] = __floats2half2_rn(att1[2 * c], att1[2 * c + 1]);
        }
    }
}

// scan A: one block per bucket k; exclusive scan of bhist[b][k] over the 196 front
// blocks -> bases[b][k], total -> btot[k]. All buckets in parallel.
__global__ __launch_bounds__(256) void scan_a_kernel(
        const int* __restrict__ bhist, int* __restrict__ bases, int* __restrict__ btot) {
    __shared__ int lds[256];
    int k = blockIdx.x;
    int t = threadIdx.x;
    int v = (t < NB1) ? bhist[t * NBUCK + k] : 0;
    lds[t] = v;
    __syncthreads();
    for (int off = 1; off < 256; off <<= 1) {
        int x = (t >= off) ? lds[t - off] : 0;
        __syncthreads();
        lds[t] += x;
        __syncthreads();
    }
    if (t < NB1) bases[t * NBUCK + k] = lds[t] - v;
    if (t == NB1 - 1) btot[k] = lds[t];
}

// scan B: single block, chunked exclusive scan of 1563 bucket totals -> cb_start.
__global__ __launch_bounds__(1024) void scan_b_kernel(
        const int* __restrict__ btot, int* __restrict__ cb_start) {
    __shared__ int lds[1024];
    __shared__ int carry_s;
    int t = threadIdx.x;
    if (t == 0) carry_s = 0;
    __syncthreads();
    for (int base0 = 0; base0 < NBUCK; base0 += 1024) {
        int idx = base0 + t;
        int v = (idx < NBUCK) ? btot[idx] : 0;
        lds[t] = v;
        __syncthreads();
        for (int off = 1; off < 1024; off <<= 1) {
            int x = (t >= off) ? lds[t - off] : 0;
            __syncthreads();
            lds[t] += x;
            __syncthreads();
        }
        int carry = carry_s;
        if (idx < NBUCK) cb_start[idx] = carry + lds[t] - v;
        __syncthreads();
        if (t == 1023) carry_s = carry + lds[1023];
        __syncthreads();
    }
    if (t == 0) cb_start[NBUCK] = carry_s;
}

// coarse scatter: edge -> bucket-grouped tmp
__global__ void coarse_scatter_kernel(const int* __restrict__ src, const int* __restrict__ dst,
                                      const int* __restrict__ rank1, const int* __restrict__ bases,
                                      const int* __restrict__ cb_start,
                                      const float* __restrict__ edge_attr,
                                      int4* __restrict__ tmp) {
    int e = blockIdx.x * blockDim.x + threadIdx.x;
    if (e >= N_EDGES) return;
    int d = dst[e];
    int k = d >> BSH;
    int b = e / EPB1;
    int slot = cb_start[k] + bases[b * NBUCK + k] + rank1[e];
    float4 ea = ((const float4*)edge_attr)[e];
    __half2 h01 = __floats2half2_rn(ea.x, ea.y);
    __half2 h23 = __floats2half2_rn(ea.z, ea.w);
    int4 ent;
    ent.x = src[e];
    ent.y = *reinterpret_cast<int*>(&h01);
    ent.z = *reinterpret_cast<int*>(&h23);
    ent.w = d;
    tmp[slot] = ent;
}

// ---------------- fused GAT layer: one block per 32-node bucket ----------------
// Phase 1: lane = edge; score from tmp (xr window 4KB L1-hot), LDS hist+scan,
// scatter (src, p=exp(s)) into node-sorted LDS slots. Phase 2: half-wave per edge;
// pairs via LDS broadcast, coalesced 128B xl-row gather (L1/L2-warm from phase 1).
// No-max softmax (scores O(+-2)); no csr/srcs/escore globals at all.
__global__ __launch_bounds__(256) void gat_layer_kernel(
        const int* __restrict__ cb_start, const int4* __restrict__ tmp,
        const __half2* __restrict__ xlh, const __half2* __restrict__ xrh,
        const __half2* __restrict__ weh, const __half2* __restrict__ atth,
        const float* __restrict__ bias, float* __restrict__ out) {
    __shared__ int2 pairs[CAP];
    __shared__ int hist[BNODES];
    __shared__ int base[BNODES + 1];
    __shared__ int cursor[BNODES];
    int k = blockIdx.x;
    int t = threadIdx.x;
    int beg = cb_start[k], end = cb_start[k + 1];
    int m = end - beg;
    if (t < BNODES) hist[t] = 0;
    __syncthreads();
    // hist pass: read only the dst word
    const int* tw = (const int*)tmp;
    for (int i = t; i < m; i += 256)
        atomicAdd(&hist[tw[4 * (beg + i) + 3] & (BNODES - 1)], 1);
    __syncthreads();
    if (t < 64) {                                  // wave 0 scans the 32 counts
        int v = (t < BNODES) ? hist[t] : 0;
        int sc = v;
#pragma unroll
        for (int off = 1; off < 64; off <<= 1) {
            int x = __shfl_up(sc, off, 64);
            if (t >= off) sc += x;
        }
        if (t < BNODES) { base[t] = sc - v; cursor[t] = sc - v; }
        if (t == BNODES - 1) base[BNODES] = sc;
    }
    __syncthreads();
    // score + scatter to sorted LDS slots (tmp window ~16KB, L1-hot re-read)
    for (int i = t; i < m; i += 256) {
        int4 ent = tmp[beg + i];
        float p = __expf(gat_score(ent, xlh, xrh, weh, atth));
        int slot = atomicAdd(&cursor[ent.w & (BNODES - 1)], 1);
        pairs[slot] = int2{ent.x, __float_as_int(p)};
    }
    __syncthreads();
    // per-node aggregation: wave w -> nodes w, w+4, ...
    int w = t >> 6, lane = t & 63, c = lane & 31, hb = lane >> 5;
    int nb = k << BSH;
    for (int n = w; n < BNODES; n += 4) {
        int node = nb + n;
        if (node >= N_NODES) break;                // only tail bucket
        int s0 = base[n], s1 = base[n + 1];
        float l = 0.f, ax0 = 0.f, ay0 = 0.f, ax1 = 0.f, ay1 = 0.f;
        int j = s0 + hb;                           // hb-split: even/odd edge offsets
        for (; j + 2 < s1; j += 4) {
            int2 prA = pairs[j];
            int2 prB = pairs[j + 2];
            float pA = __int_as_float(prA.y), pB = __int_as_float(prB.y);
            float2 xA = __half22float2(xlh[prA.x * 32 + c]);
            float2 xB = __half22float2(xlh[prB.x * 32 + c]);
            ax0 += pA * xA.x; ay0 += pA * xA.y; l += pA;
            ax1 += pB * xB.x; ay1 += pB * xB.y; l += pB;
        }
        if (j < s1) {
            int2 pr = pairs[j];
            float p = __int_as_float(pr.y);
            float2 xf = __half22float2(xlh[pr.x * 32 + c]);
            ax0 += p * xf.x; ay0 += p * xf.y; l += p;
        }
        float accx = ax0 + ax1, accy = ay0 + ay1;
        accx += __shfl_xor(accx, 32, 64);
        accy += __shfl_xor(accy, 32, 64);
        l += __shfl_xor(l, 32, 64);
        if (hb == 0) {
            float inv = 1.f / (l + 1e-16f);
            float2 b2 = ((const float2*)bias)[c];
            float o0 = accx * inv + b2.x;
            float o1 = accy * inv + b2.y;
            o0 = o0 > 0.f ? o0 : expm1f(o0);
            o1 = o1 > 0.f ? o1 : expm1f(o1);
            ((float2*)out)[node * 32 + c] = float2{o0, o1};
        }
    }
}

// ---------------- layer-1 projection: lane = node, scalar weights ----------------
__global__ __launch_bounds__(256) void proj1_kernel(
        const float* __restrict__ xin,
        const __half2* __restrict__ wt,
        const float* __restrict__ bb,
        __half2* __restrict__ xlh, __half2* __restrict__ xrh) {
    int g = __builtin_amdgcn_readfirstlane((int)(threadIdx.x >> 6));
    int lane = threadIdx.x & 63;
    int node = blockIdx.x * 64 + lane;
    if (node >= N_NODES) return;

    h2v xrow[32];
    const float4* xp = (const float4*)(xin + node * 64);
#pragma unroll
    for (int q = 0; q < 16; ++q) {
        float4 v = xp[q];
        __half2 a = __floats2half2_rn(v.x, v.y);
        __half2 b = __floats2half2_rn(v.z, v.w);
        xrow[2 * q]     = *reinterpret_cast<h2v*>(&a);
        xrow[2 * q + 1] = *reinterpret_cast<h2v*>(&b);
    }

    __half2* outp = (g < 2) ? xlh : xrh;
    int chbase = g * 32;
    int localbase = (g & 1) * 16;

#pragma unroll
    for (int cp = 0; cp < 16; ++cp) {
        int ch0 = chbase + 2 * cp;
        const h2v* w0 = (const h2v*)(wt + ch0 * 32);
        const h2v* w1 = (const h2v*)(wt + (ch0 + 1) * 32);
        float a0 = bb[ch0], a1 = bb[ch0 + 1];
#pragma unroll
        for (int kk = 0; kk < 32; ++kk) {
            a0 = fdot2f(xrow[kk], w0[kk], a0);
            a1 = fdot2f(xrow[kk], w1[kk], a1);
        }
        outp[node * 32 + localbase + cp] = __floats2half2_rn(a0, a1);
    }
}

// ---------------- fused pool + head: one block per graph ----------------
__global__ __launch_bounds__(256) void pool_head_kernel(
        const float* __restrict__ h, const int* __restrict__ batch,
        const float* __restrict__ fc1w, const float* __restrict__ fc1b,
        const float* __restrict__ fc2w, const float* __restrict__ fc2b,
        float* __restrict__ out) {
    int g = blockIdx.x;
    int lo = 0, hi = N_NODES;
    while (lo < hi) { int mid = (lo + hi) >> 1; if (batch[mid] < g) lo = mid + 1; else hi = mid; }
    int start = lo;
    hi = N_NODES;
    while (lo < hi) { int mid = (lo + hi) >> 1; if (batch[mid] < g + 1) lo = mid + 1; else hi = mid; }
    int end = lo;

    int lane = threadIdx.x & 63;
    int w = threadIdx.x >> 6;
    float s = 0.f;
    for (int n = start + w; n < end; n += 4) s += h[n * H + lane];
    __shared__ float red[4][H];
    __shared__ float gv[H];
    __shared__ float f[FC];
    __shared__ float lg[NC];
    red[w][lane] = s;
    __syncthreads();
    if (w == 0) {
        float tot = red[0][lane] + red[1][lane] + red[2][lane] + red[3][lane];
        gv[lane] = tot / fmaxf((float)(end - start), 1.f);
    }
    __syncthreads();
    int t = threadIdx.x;
    if (t < FC) {
        float acc = fc1b[t];
#pragma unroll 16
        for (int k = 0; k < H; ++k) acc += gv[k] * fc1w[k * FC + t];
        f[t] = fmaxf(acc, 0.f);
    }
    __syncthreads();
    if (t < NC) {
        float a = fc2b[t];
        for (int k = 0; k < FC; ++k) a += f[k] * fc2w[k * NC + t];
        lg[t] = a;
    }
    __syncthreads();
    if (t < NC) {
        float mx = fmaxf(lg[0], lg[1]);
        float lse = mx + logf(expf(lg[0] - mx) + expf(lg[1] - mx));
        out[g * NC + t] = lg[t] - lse;
    }
}

extern "C" void kernel_launch(void* const* d_in, const int* in_sizes, int n_in,
                              void* d_out, int out_size, void* d_ws, size_t ws_size,
                              hipStream_t stream) {
    const float* x         = (const float*)d_in[0];
    const int*   edge_idx  = (const int*)d_in[1];
    const float* edge_attr = (const float*)d_in[2];
    const int*   batch     = (const int*)d_in[3];
    const float* Wl0  = (const float*)d_in[4];
    const float* bl0  = (const float*)d_in[5];
    const float* Wr0  = (const float*)d_in[6];
    const float* br0  = (const float*)d_in[7];
    const float* We0  = (const float*)d_in[8];
    const float* att0 = (const float*)d_in[9];
    const float* bias0= (const float*)d_in[10];
    const float* Wl1  = (const float*)d_in[11];
    const float* bl1  = (const float*)d_in[12];
    const float* Wr1  = (const float*)d_in[13];
    const float* br1  = (const float*)d_in[14];
    const float* We1  = (const float*)d_in[15];
    const float* att1 = (const float*)d_in[16];
    const float* bias1= (const float*)d_in[17];
    const float* fc1w = (const float*)d_in[18];
    const float* fc1b = (const float*)d_in[19];
    const float* fc2w = (const float*)d_in[20];
    const float* fc2b = (const float*)d_in[21];

    // ---- workspace layout (tmp is live through both gat_layer calls -> no aliasing with C) ----
    __half2* xlh    = (__half2*)d_ws;                 // [N*32]
    __half2* xrh    = xlh + N_NODES * 32;             // [N*32]
    float* C        = (float*)(xrh + N_NODES * 32);   // [N,64] fp32
    int4*  tmp      = (int4*)(C + N_NODES * 64);      // [E] bucket-grouped edges
    int*   rank1    = (int*)(tmp + N_EDGES);          // [E]
    int*   bhist    = rank1 + N_EDGES;                // [NB1*NBUCK]
    int*   bases    = bhist + NB1 * NBUCK;            // [NB1*NBUCK]
    int*   btot     = bases + NB1 * NBUCK;            // [NBUCK]
    int*   cb_start = btot + NBUCK;                   // [NBUCK+1]
    __half2* weh0   = (__half2*)(cb_start + NBUCK + 1);
    __half2* weh1   = weh0 + 128;
    __half2* wt1    = weh1 + 128;                     // [128*32]
    float* bb1      = (float*)(wt1 + 128 * 32);       // [128]
    __half2* atth0  = (__half2*)(bb1 + 128);          // [32]
    __half2* atth1  = atth0 + 32;                     // [32]

    const int* src = edge_idx;
    const int* dst = edge_idx + N_EDGES;

    const int edgeBlocks = (N_EDGES + 255) / 256;
    const int p1Blocks   = (N_NODES + 63) / 64;
    const int frontBlocks = NB1 + PAIR_BLOCKS + 1;

    // ---- bucket-CSR build via 2-pass radix (LDS atomics, parallel scans) + proj0 + prep ----
    front_kernel<<<frontBlocks, 256, 0, stream>>>(dst, rank1, bhist,
                                                  x, Wl0, bl0, Wr0, br0, xlh, xrh,
                                                  We0, We1, Wl1, bl1, Wr1, br1,
                                                  weh0, weh1, wt1, bb1,
                                                  att0, att1, atth0, atth1);
    scan_a_kernel<<<NBUCK, 256, 0, stream>>>(bhist, bases, btot);
    scan_b_kernel<<<1, 1024, 0, stream>>>(btot, cb_start);
    coarse_scatter_kernel<<<edgeBlocks, 256, 0, stream>>>(src, dst, rank1, bases, cb_start,
                                                          edge_attr, tmp);

    // ---- layer 0 (fused sort+score+softmax+aggregate in LDS) ----
    gat_layer_kernel<<<NBUCK, 256, 0, stream>>>(cb_start, tmp, xlh, xrh,
                                                weh0, atth0, bias0, C);

    // ---- layer 1 ----
    proj1_kernel<<<p1Blocks, 256, 0, stream>>>(C, wt1, bb1, xlh, xrh);
    gat_layer_kernel<<<NBUCK, 256, 0, stream>>>(cb_start, tmp, xlh, xrh,
                                                weh1, atth1, bias1, C);

    // ---- pool + head (fused) ----
    pool_head_kernel<<<G_GRAPHS, 256, 0, stream>>>(C, batch, fc1w, fc1b, fc2w, fc2b, (float*)d_out);
}

// Round 9
// 407.415 us; speedup vs baseline: 1.0762x; 1.0762x over previous
//
#include <hip/hip_runtime.h>
#include <hip/hip_fp16.h>

#define N_NODES 50000
#define N_EDGES 1600000
#define H 64
#define IN_CH 7
#define EDIM 4
#define G_GRAPHS 256
#define FC 128
#define NC 2
#define SLOPE 0.2f
#define BSH 6                           // bucket shift: 64 nodes per bucket
#define BNODES 64
#define NBUCK ((N_NODES + BNODES - 1) / BNODES)    // 782
#define EPB1 8192                       // edges per front hist block
#define NB1 ((N_EDGES + EPB1 - 1) / EPB1)          // 196
#define PAIR_BLOCKS ((N_NODES * 32 + 255) / 256)   // 6250

typedef _Float16 h2v __attribute__((ext_vector_type(2)));

__device__ __forceinline__ float fdot2f(h2v a, h2v b, float c) {
#if defined(__has_builtin) && __has_builtin(__builtin_amdgcn_fdot2)
    return __builtin_amdgcn_fdot2(a, b, c, false);
#else
    return c + (float)a[0] * (float)b[0] + (float)a[1] * (float)b[1];
#endif
}

// ---------------- DPP wave-64 reductions ----------------
__device__ __forceinline__ float wave_sum_to63(float x) {
    x += __int_as_float(__builtin_amdgcn_update_dpp(0, __float_as_int(x), 0x111, 0xf, 0xf, true)); // row_shr:1
    x += __int_as_float(__builtin_amdgcn_update_dpp(0, __float_as_int(x), 0x112, 0xf, 0xf, true)); // row_shr:2
    x += __int_as_float(__builtin_amdgcn_update_dpp(0, __float_as_int(x), 0x114, 0xf, 0xf, true)); // row_shr:4
    x += __int_as_float(__builtin_amdgcn_update_dpp(0, __float_as_int(x), 0x118, 0xf, 0xf, true)); // row_shr:8
    x += __int_as_float(__builtin_amdgcn_update_dpp(0, __float_as_int(x), 0x142, 0xf, 0xf, true)); // row_bcast:15
    x += __int_as_float(__builtin_amdgcn_update_dpp(0, __float_as_int(x), 0x143, 0xf, 0xf, true)); // row_bcast:31
    return x;
}
__device__ __forceinline__ float lane63_bcast(float x) {
    return __int_as_float(__builtin_amdgcn_readlane(__float_as_int(x), 63));
}
__device__ __forceinline__ float readlane_f(float x, int i) {
    return __int_as_float(__builtin_amdgcn_readlane(__float_as_int(x), i));
}

// ---------------- fused front-end: coarse histogram+rank (LDS atomics) + proj0 + prep ----------------
__global__ __launch_bounds__(256) void front_kernel(
        const int* __restrict__ dst, int* __restrict__ rank1, int* __restrict__ bhist,
        const float* __restrict__ xin,
        const float* __restrict__ Wl0, const float* __restrict__ bl0,
        const float* __restrict__ Wr0, const float* __restrict__ br0,
        __half2* __restrict__ xlh, __half2* __restrict__ xrh,
        const float* __restrict__ We0, const float* __restrict__ We1,
        const float* __restrict__ Wl1, const float* __restrict__ bl1,
        const float* __restrict__ Wr1, const float* __restrict__ br1,
        __half2* __restrict__ weh0, __half2* __restrict__ weh1,
        __half2* __restrict__ wt, float* __restrict__ bb,
        const float* __restrict__ att0, const float* __restrict__ att1,
        __half2* __restrict__ atth0, __half2* __restrict__ atth1) {
    __shared__ int hist[NBUCK];
    int b = blockIdx.x;
    int t = threadIdx.x;
    if (b < NB1) {
        for (int i = t; i < NBUCK; i += 256) hist[i] = 0;
        __syncthreads();
#pragma unroll
        for (int i = 0; i < EPB1 / 256; ++i) {
            int e = b * EPB1 + i * 256 + t;
            if (e < N_EDGES) {
                int k = dst[e] >> BSH;
                rank1[e] = atomicAdd(&hist[k], 1);
            }
        }
        __syncthreads();
        for (int i = t; i < NBUCK; i += 256) bhist[b * NBUCK + i] = hist[i];
    } else if (b < NB1 + PAIR_BLOCKS) {
        int idx = (b - NB1) * 256 + t;
        if (idx < N_NODES * 32) {
            int n = idx >> 5;
            int c = idx & 31;
            const float* xi = xin + n * IN_CH;
            float2 bl2 = ((const float2*)bl0)[c];
            float2 br2 = ((const float2*)br0)[c];
            float al0 = bl2.x, al1 = bl2.y, ar0 = br2.x, ar1 = br2.y;
#pragma unroll
            for (int k = 0; k < IN_CH; ++k) {
                float xv = xi[k];
                float2 wl2 = ((const float2*)(Wl0 + k * H))[c];
                float2 wr2 = ((const float2*)(Wr0 + k * H))[c];
                al0 += xv * wl2.x; al1 += xv * wl2.y;
                ar0 += xv * wr2.x; ar1 += xv * wr2.y;
            }
            xlh[idx] = __floats2half2_rn(al0, al1);
            xrh[idx] = __floats2half2_rn(ar0, ar1);
        }
    } else {
        if (t < 32) {
            for (int k = 0; k < 4; ++k)
                weh0[t * 4 + k] = __floats2half2_rn(We0[k * H + 2 * t], We0[k * H + 2 * t + 1]);
        } else if (t < 64) {
            int c = t - 32;
            for (int k = 0; k < 4; ++k)
                weh1[c * 4 + k] = __floats2half2_rn(We1[k * H + 2 * c], We1[k * H + 2 * c + 1]);
        }
        if (t < 128) {
            const float* W = (t < 64) ? Wl1 : Wr1;
            int c = t & 63;
            for (int kk = 0; kk < 32; ++kk)
                wt[t * 32 + kk] = __floats2half2_rn(W[(2 * kk) * H + c], W[(2 * kk + 1) * H + c]);
            bb[t] = (t < 64) ? bl1[c] : br1[c];
        } else if (t < 160) {
            int c = t - 128;
            atth0[c] = __floats2half2_rn(att0[2 * c], att0[2 * c + 1]);
            atth1[c] = __floats2half2_rn(att1[2 * c], att1[2 * c + 1]);
        }
    }
}

// scan A: one block per bucket k; exclusive scan of bhist[b][k] over the 196 front
// blocks -> bases[b][k], total -> btot[k]. All buckets in parallel.
__global__ __launch_bounds__(256) void scan_a_kernel(
        const int* __restrict__ bhist, int* __restrict__ bases, int* __restrict__ btot) {
    __shared__ int lds[256];
    int k = blockIdx.x;
    int t = threadIdx.x;
    int v = (t < NB1) ? bhist[t * NBUCK + k] : 0;
    lds[t] = v;
    __syncthreads();
    for (int off = 1; off < 256; off <<= 1) {
        int x = (t >= off) ? lds[t - off] : 0;
        __syncthreads();
        lds[t] += x;
        __syncthreads();
    }
    if (t < NB1) bases[t * NBUCK + k] = lds[t] - v;
    if (t == NB1 - 1) btot[k] = lds[t];
}

// scan B: single block, exclusive scan of 782 bucket totals -> cb_start.
__global__ __launch_bounds__(1024) void scan_b_kernel(
        const int* __restrict__ btot, int* __restrict__ cb_start) {
    __shared__ int lds[1024];
    int t = threadIdx.x;
    int v = (t < NBUCK) ? btot[t] : 0;
    lds[t] = v;
    __syncthreads();
    for (int off = 1; off < 1024; off <<= 1) {
        int x = (t >= off) ? lds[t - off] : 0;
        __syncthreads();
        lds[t] += x;
        __syncthreads();
    }
    if (t < NBUCK) cb_start[t] = lds[t] - v;
    if (t == NBUCK - 1) cb_start[NBUCK] = lds[t];
}

// coarse scatter: edge -> bucket-sorted tmp (block-sequential slots within bucket)
__global__ void coarse_scatter_kernel(const int* __restrict__ src, const int* __restrict__ dst,
                                      const int* __restrict__ rank1, const int* __restrict__ bases,
                                      const int* __restrict__ cb_start,
                                      const float* __restrict__ edge_attr,
                                      int4* __restrict__ tmp) {
    int e = blockIdx.x * blockDim.x + threadIdx.x;
    if (e >= N_EDGES) return;
    int d = dst[e];
    int k = d >> BSH;
    int b = e / EPB1;
    int slot = cb_start[k] + bases[b * NBUCK + k] + rank1[e];
    float4 ea = ((const float4*)edge_attr)[e];
    __half2 h01 = __floats2half2_rn(ea.x, ea.y);
    __half2 h23 = __floats2half2_rn(ea.z, ea.w);
    int4 ent;
    ent.x = src[e];
    ent.y = *reinterpret_cast<int*>(&h01);
    ent.z = *reinterpret_cast<int*>(&h23);
    ent.w = d;
    tmp[slot] = ent;
}

// fine sort: one block per 64-node bucket (782 blocks); emits csr + srcs + row_start.
__global__ __launch_bounds__(256) void fine_sort_kernel(
        const int* __restrict__ cb_start, const int4* __restrict__ tmp,
        int4* __restrict__ csr, int* __restrict__ srcs,
        int* __restrict__ row_start) {
    __shared__ int hist2[BNODES];
    __shared__ int cursor[BNODES];
    __shared__ int lds[BNODES];
    int k = blockIdx.x;
    int t = threadIdx.x;
    int beg = cb_start[k], end = cb_start[k + 1];
    if (t < BNODES) hist2[t] = 0;
    __syncthreads();
    for (int i = beg + t; i < end; i += 256)
        atomicAdd(&hist2[tmp[i].w & (BNODES - 1)], 1);
    __syncthreads();
    int v = 0;
    if (t < BNODES) { v = hist2[t]; lds[t] = v; }
    __syncthreads();
    for (int off = 1; off < BNODES; off <<= 1) {
        int x = (t < BNODES && t >= off) ? lds[t - off] : 0;
        __syncthreads();
        if (t < BNODES) lds[t] += x;
        __syncthreads();
    }
    if (t < BNODES) {
        int pre = lds[t] - v;
        cursor[t] = pre;
        int node = (k << BSH) + t;
        if (node <= N_NODES) row_start[node] = beg + pre;
    }
    __syncthreads();
    for (int i = beg + t; i < end; i += 256) {
        int4 ent = tmp[i];
        int slot = beg + atomicAdd(&cursor[ent.w & (BNODES - 1)], 1);
        csr[slot] = ent;
        srcs[slot] = ent.x;
    }
}

// ---------------- layer-1 projection: lane = node, scalar weights ----------------
__global__ __launch_bounds__(256) void proj1_kernel(
        const float* __restrict__ xin,
        const __half2* __restrict__ wt,
        const float* __restrict__ bb,
        __half2* __restrict__ xlh, __half2* __restrict__ xrh) {
    int g = __builtin_amdgcn_readfirstlane((int)(threadIdx.x >> 6));
    int lane = threadIdx.x & 63;
    int node = blockIdx.x * 64 + lane;
    if (node >= N_NODES) return;

    h2v xrow[32];
    const float4* xp = (const float4*)(xin + node * 64);
#pragma unroll
    for (int q = 0; q < 16; ++q) {
        float4 v = xp[q];
        __half2 a = __floats2half2_rn(v.x, v.y);
        __half2 b = __floats2half2_rn(v.z, v.w);
        xrow[2 * q]     = *reinterpret_cast<h2v*>(&a);
        xrow[2 * q + 1] = *reinterpret_cast<h2v*>(&b);
    }

    __half2* outp = (g < 2) ? xlh : xrh;
    int chbase = g * 32;
    int localbase = (g & 1) * 16;

#pragma unroll
    for (int cp = 0; cp < 16; ++cp) {
        int ch0 = chbase + 2 * cp;
        const h2v* w0 = (const h2v*)(wt + ch0 * 32);
        const h2v* w1 = (const h2v*)(wt + (ch0 + 1) * 32);
        float a0 = bb[ch0], a1 = bb[ch0 + 1];
#pragma unroll
        for (int kk = 0; kk < 32; ++kk) {
            a0 = fdot2f(xrow[kk], w0[kk], a0);
            a1 = fdot2f(xrow[kk], w1[kk], a1);
        }
        outp[node * 32 + localbase + cp] = __floats2half2_rn(a0, a1);
    }
}

// ---------------- per-edge score: 2 edges per thread, interleaved chains ----------------
__global__ __launch_bounds__(256) void score2_kernel(
        const int4* __restrict__ csr,
        const __half2* __restrict__ xlh, const __half2* __restrict__ xrh,
        const __half2* __restrict__ weh, const __half2* __restrict__ atth,
        float* __restrict__ score) {
    int base = blockIdx.x * 512 + threadIdx.x;     // N_EDGES % 512 == 0
    int4 entA = csr[base];
    int4 entB = csr[base + 256];
    __half2 eaA01 = *reinterpret_cast<__half2*>(&entA.y);
    __half2 eaA23 = *reinterpret_cast<__half2*>(&entA.z);
    __half2 a0 = __half2half2(__low2half(eaA01));
    __half2 a1 = __half2half2(__high2half(eaA01));
    __half2 a2 = __half2half2(__low2half(eaA23));
    __half2 a3 = __half2half2(__high2half(eaA23));
    __half2 eaB01 = *reinterpret_cast<__half2*>(&entB.y);
    __half2 eaB23 = *reinterpret_cast<__half2*>(&entB.z);
    __half2 b0 = __half2half2(__low2half(eaB01));
    __half2 b1 = __half2half2(__high2half(eaB01));
    __half2 b2 = __half2half2(__low2half(eaB23));
    __half2 b3 = __half2half2(__high2half(eaB23));
    const h2v sl = { (_Float16)SLOPE, (_Float16)SLOPE };
    const int4* xaA = (const int4*)(xlh + (size_t)entA.x * 32);
    const int4* xbA = (const int4*)(xrh + (size_t)entA.w * 32);
    const int4* xaB = (const int4*)(xlh + (size_t)entB.x * 32);
    const int4* xbB = (const int4*)(xrh + (size_t)entB.w * 32);
    float accA0 = 0.f, accA1 = 0.f, accB0 = 0.f, accB1 = 0.f;
#pragma unroll
    for (int k = 0; k < 8; ++k) {
        int4 vaA = xaA[k];
        int4 vbA = xbA[k];
        int4 vaB = xaB[k];
        int4 vbB = xbB[k];
        const __half2* haA = reinterpret_cast<const __half2*>(&vaA);
        const __half2* hcA = reinterpret_cast<const __half2*>(&vbA);
        const __half2* haB = reinterpret_cast<const __half2*>(&vaB);
        const __half2* hcB = reinterpret_cast<const __half2*>(&vbB);
#pragma unroll
        for (int j = 0; j < 4; ++j) {
            int c = k * 4 + j;                     // uniform -> scalar weight loads
            __half2 w0 = weh[c * 4 + 0];
            __half2 w1 = weh[c * 4 + 1];
            __half2 w2 = weh[c * 4 + 2];
            __half2 w3 = weh[c * 4 + 3];
            __half2 av = atth[c];
            __half2 vA = __hadd2(haA[j], hcA[j]);
            vA = __hfma2(a0, w0, vA);
            vA = __hfma2(a1, w1, vA);
            vA = __hfma2(a2, w2, vA);
            vA = __hfma2(a3, w3, vA);
            __half2 vB = __hadd2(haB[j], hcB[j]);
            vB = __hfma2(b0, w0, vB);
            vB = __hfma2(b1, w1, vB);
            vB = __hfma2(b2, w2, vB);
            vB = __hfma2(b3, w3, vB);
            h2v vvA = *reinterpret_cast<h2v*>(&vA);
            h2v LA = __builtin_elementwise_max(vvA, sl * vvA);
            h2v vvB = *reinterpret_cast<h2v*>(&vB);
            h2v LB = __builtin_elementwise_max(vvB, sl * vvB);
            h2v avv = *reinterpret_cast<h2v*>(&av);
            if (j & 1) {
                accA1 = fdot2f(LA, avv, accA1);
                accB1 = fdot2f(LB, avv, accB1);
            } else {
                accA0 = fdot2f(LA, avv, accA0);
                accB0 = fdot2f(LB, avv, accB0);
            }
        }
    }
    score[base] = accA0 + accA1;
    score[base + 256] = accB0 + accB1;
}

// ---------------- aggregation: one wave per node (no max subtraction) ----------------
__global__ __launch_bounds__(256) void agg_kernel(
        const int* __restrict__ row_start,
        const int* __restrict__ srcs,
        const float* __restrict__ score,
        const __half2* __restrict__ xlh,
        const float* __restrict__ bias,
        float* __restrict__ out) {
    int wave = (blockIdx.x * blockDim.x + threadIdx.x) >> 6;
    if (wave >= N_NODES) return;
    int lane = threadIdx.x & 63;
    int c = lane & 31;
    int hb = lane >> 5;
    int d = wave;
    int beg = __builtin_amdgcn_readfirstlane(row_start[d]);
    int end = __builtin_amdgcn_readfirstlane(row_start[d + 1]);

    float l_lane = 0.f;
    float ax0 = 0.f, ay0 = 0.f, ax1 = 0.f, ay1 = 0.f;

    for (int cbeg = beg; cbeg < end; cbeg += 64) {
        int n = end - cbeg;
        float sc = score[cbeg + lane];        // reads past end land in pad; masked below
        float p = __expf(sc);
        p = (lane < n) ? p : 0.f;
        l_lane += p;

        int nn = min(n, 64);
        int j = 0;
        for (; j + 8 <= nn; j += 8) {         // 8-wide: 4 gathers in flight per half-wave
            int s0 = __builtin_amdgcn_readfirstlane(srcs[cbeg + j + 0]);
            int s1 = __builtin_amdgcn_readfirstlane(srcs[cbeg + j + 1]);
            int s2 = __builtin_amdgcn_readfirstlane(srcs[cbeg + j + 2]);
            int s3 = __builtin_amdgcn_readfirstlane(srcs[cbeg + j + 3]);
            int s4 = __builtin_amdgcn_readfirstlane(srcs[cbeg + j + 4]);
            int s5 = __builtin_amdgcn_readfirstlane(srcs[cbeg + j + 5]);
            int s6 = __builtin_amdgcn_readfirstlane(srcs[cbeg + j + 6]);
            int s7 = __builtin_amdgcn_readfirstlane(srcs[cbeg + j + 7]);
            float p0 = readlane_f(p, j + 0), p1 = readlane_f(p, j + 1);
            float p2 = readlane_f(p, j + 2), p3 = readlane_f(p, j + 3);
            float p4 = readlane_f(p, j + 4), p5 = readlane_f(p, j + 5);
            float p6 = readlane_f(p, j + 6), p7 = readlane_f(p, j + 7);
            int g0 = hb ? s1 : s0;
            int g1 = hb ? s3 : s2;
            int g2 = hb ? s5 : s4;
            int g3 = hb ? s7 : s6;
            float q0 = hb ? p1 : p0;
            float q1 = hb ? p3 : p2;
            float q2 = hb ? p5 : p4;
            float q3 = hb ? p7 : p6;
            float2 x0 = __half22float2(xlh[g0 * 32 + c]);
            float2 x1 = __half22float2(xlh[g1 * 32 + c]);
            float2 x2 = __half22float2(xlh[g2 * 32 + c]);
            float2 x3 = __half22float2(xlh[g3 * 32 + c]);
            ax0 += q0 * x0.x; ay0 += q0 * x0.y;
            ax1 += q1 * x1.x; ay1 += q1 * x1.y;
            ax0 += q2 * x2.x; ay0 += q2 * x2.y;
            ax1 += q3 * x3.x; ay1 += q3 * x3.y;
        }
        for (; j + 4 <= nn; j += 4) {
            int sA0 = __builtin_amdgcn_readfirstlane(srcs[cbeg + j + 0]);
            int sB0 = __builtin_amdgcn_readfirstlane(srcs[cbeg + j + 1]);
            int sA1 = __builtin_amdgcn_readfirstlane(srcs[cbeg + j + 2]);
            int sB1 = __builtin_amdgcn_readfirstlane(srcs[cbeg + j + 3]);
            float pA0 = readlane_f(p, j + 0), pB0 = readlane_f(p, j + 1);
            float pA1 = readlane_f(p, j + 2), pB1 = readlane_f(p, j + 3);
            int s0 = hb ? sB0 : sA0;
            int s1 = hb ? sB1 : sA1;
            float pv0 = hb ? pB0 : pA0;
            float pv1 = hb ? pB1 : pA1;
            float2 x0 = __half22float2(xlh[s0 * 32 + c]);
            float2 x1 = __half22float2(xlh[s1 * 32 + c]);
            ax0 += pv0 * x0.x; ay0 += pv0 * x0.y;
            ax1 += pv1 * x1.x; ay1 += pv1 * x1.y;
        }
        for (; j + 2 <= nn; j += 2) {
            int sA = __builtin_amdgcn_readfirstlane(srcs[cbeg + j + 0]);
            int sB = __builtin_amdgcn_readfirstlane(srcs[cbeg + j + 1]);
            float pA = readlane_f(p, j + 0), pB = readlane_f(p, j + 1);
            int s = hb ? sB : sA;
            float pv = hb ? pB : pA;
            float2 xf = __half22float2(xlh[s * 32 + c]);
            ax0 += pv * xf.x; ay0 += pv * xf.y;
        }
        if (j < nn) {
            int sA = __builtin_amdgcn_readfirstlane(srcs[cbeg + j]);
            float pA = readlane_f(p, j);
            float pv = hb ? 0.f : pA;
            float2 xf = __half22float2(xlh[sA * 32 + c]);
            ax0 += pv * xf.x; ay0 += pv * xf.y;
        }
    }

    float l = lane63_bcast(wave_sum_to63(l_lane));
    float accx = ax0 + ax1, accy = ay0 + ay1;
    accx += __shfl_xor(accx, 32, 64);
    accy += __shfl_xor(accy, 32, 64);
    if (hb == 0) {
        float inv = 1.f / (l + 1e-16f);
        float2 b2 = ((const float2*)bias)[c];
        float o0 = accx * inv + b2.x;
        float o1 = accy * inv + b2.y;
        o0 = o0 > 0.f ? o0 : expm1f(o0);
        o1 = o1 > 0.f ? o1 : expm1f(o1);
        ((float2*)out)[d * 32 + c] = float2{o0, o1};
    }
}

// ---------------- fused pool + head: one block per graph ----------------
__global__ __launch_bounds__(256) void pool_head_kernel(
        const float* __restrict__ h, const int* __restrict__ batch,
        const float* __restrict__ fc1w, const float* __restrict__ fc1b,
        const float* __restrict__ fc2w, const float* __restrict__ fc2b,
        float* __restrict__ out) {
    int g = blockIdx.x;
    int lo = 0, hi = N_NODES;
    while (lo < hi) { int mid = (lo + hi) >> 1; if (batch[mid] < g) lo = mid + 1; else hi = mid; }
    int start = lo;
    hi = N_NODES;
    while (lo < hi) { int mid = (lo + hi) >> 1; if (batch[mid] < g + 1) lo = mid + 1; else hi = mid; }
    int end = lo;

    int lane = threadIdx.x & 63;
    int w = threadIdx.x >> 6;
    float s = 0.f;
    for (int n = start + w; n < end; n += 4) s += h[n * H + lane];
    __shared__ float red[4][H];
    __shared__ float gv[H];
    __shared__ float f[FC];
    __shared__ float lg[NC];
    red[w][lane] = s;
    __syncthreads();
    if (w == 0) {
        float tot = red[0][lane] + red[1][lane] + red[2][lane] + red[3][lane];
        gv[lane] = tot / fmaxf((float)(end - start), 1.f);
    }
    __syncthreads();
    int t = threadIdx.x;
    if (t < FC) {
        float acc = fc1b[t];
#pragma unroll 16
        for (int k = 0; k < H; ++k) acc += gv[k] * fc1w[k * FC + t];
        f[t] = fmaxf(acc, 0.f);
    }
    __syncthreads();
    if (t < NC) {
        float a = fc2b[t];
        for (int k = 0; k < FC; ++k) a += f[k] * fc2w[k * NC + t];
        lg[t] = a;
    }
    __syncthreads();
    if (t < NC) {
        float mx = fmaxf(lg[0], lg[1]);
        float lse = mx + logf(expf(lg[0] - mx) + expf(lg[1] - mx));
        out[g * NC + t] = lg[t] - lse;
    }
}

extern "C" void kernel_launch(void* const* d_in, const int* in_sizes, int n_in,
                              void* d_out, int out_size, void* d_ws, size_t ws_size,
                              hipStream_t stream) {
    const float* x         = (const float*)d_in[0];
    const int*   edge_idx  = (const int*)d_in[1];
    const float* edge_attr = (const float*)d_in[2];
    const int*   batch     = (const int*)d_in[3];
    const float* Wl0  = (const float*)d_in[4];
    const float* bl0  = (const float*)d_in[5];
    const float* Wr0  = (const float*)d_in[6];
    const float* br0  = (const float*)d_in[7];
    const float* We0  = (const float*)d_in[8];
    const float* att0 = (const float*)d_in[9];
    const float* bias0= (const float*)d_in[10];
    const float* Wl1  = (const float*)d_in[11];
    const float* bl1  = (const float*)d_in[12];
    const float* Wr1  = (const float*)d_in[13];
    const float* br1  = (const float*)d_in[14];
    const float* We1  = (const float*)d_in[15];
    const float* att1 = (const float*)d_in[16];
    const float* bias1= (const float*)d_in[17];
    const float* fc1w = (const float*)d_in[18];
    const float* fc1b = (const float*)d_in[19];
    const float* fc2w = (const float*)d_in[20];
    const float* fc2b = (const float*)d_in[21];

    // ---- workspace layout ----
    // tmp aliases [C | escore | pad] (tmp dead after fine_sort; C/escore written after).
    __half2* xlh    = (__half2*)d_ws;                 // [N*32]
    __half2* xrh    = xlh + N_NODES * 32;             // [N*32]
    float* C        = (float*)(xrh + N_NODES * 32);   // [N,64] fp32 ┐
    float* escore   = C + N_NODES * 64;               // [E]         ├ tmp aliases these
    float* pad      = escore + N_EDGES;               // [E]         ┘
    int4*  tmp      = (int4*)C;                       // [E]
    int4*  csr      = (int4*)(pad + N_EDGES);         // [E]
    int*   srcs     = (int*)(csr + N_EDGES);          // [E]
    int*   row_start= srcs + N_EDGES;                 // [N+1]
    int*   rank1    = row_start + N_NODES + 1;        // [E]
    int*   bhist    = rank1 + N_EDGES;                // [NB1*NBUCK]
    int*   bases    = bhist + NB1 * NBUCK;            // [NB1*NBUCK]
    int*   btot     = bases + NB1 * NBUCK;            // [NBUCK]
    int*   cb_start = btot + NBUCK;                   // [NBUCK+1]
    __half2* weh0   = (__half2*)(cb_start + NBUCK + 1);
    __half2* weh1   = weh0 + 128;
    __half2* wt1    = weh1 + 128;                     // [128*32]
    float* bb1      = (float*)(wt1 + 128 * 32);       // [128]
    __half2* atth0  = (__half2*)(bb1 + 128);          // [32]
    __half2* atth1  = atth0 + 32;                     // [32]

    const int* src = edge_idx;
    const int* dst = edge_idx + N_EDGES;

    const int edgeBlocks  = (N_EDGES + 255) / 256;
    const int edgeBlocks2 = N_EDGES / 512;            // 3125
    const int waveBlocks  = (N_NODES * 64 + 255) / 256;
    const int p1Blocks    = (N_NODES + 63) / 64;
    const int frontBlocks = NB1 + PAIR_BLOCKS + 1;

    // ---- CSR build via 2-pass radix (LDS atomics, parallel scans) + proj0 + prep ----
    front_kernel<<<frontBlocks, 256, 0, stream>>>(dst, rank1, bhist,
                                                  x, Wl0, bl0, Wr0, br0, xlh, xrh,
                                                  We0, We1, Wl1, bl1, Wr1, br1,
                                                  weh0, weh1, wt1, bb1,
                                                  att0, att1, atth0, atth1);
    scan_a_kernel<<<NBUCK, 256, 0, stream>>>(bhist, bases, btot);
    scan_b_kernel<<<1, 1024, 0, stream>>>(btot, cb_start);
    coarse_scatter_kernel<<<edgeBlocks, 256, 0, stream>>>(src, dst, rank1, bases, cb_start,
                                                          edge_attr, tmp);
    fine_sort_kernel<<<NBUCK, 256, 0, stream>>>(cb_start, tmp, csr, srcs, row_start);

    // ---- layer 0 ----
    score2_kernel<<<edgeBlocks2, 256, 0, stream>>>(csr, xlh, xrh, weh0, atth0, escore);
    agg_kernel<<<waveBlocks, 256, 0, stream>>>(row_start, srcs, escore, xlh, bias0, C);

    // ---- layer 1 ----
    proj1_kernel<<<p1Blocks, 256, 0, stream>>>(C, wt1, bb1, xlh, xrh);
    score2_kernel<<<edgeBlocks2, 256, 0, stream>>>(csr, xlh, xrh, weh1, atth1, escore);
    agg_kernel<<<waveBlocks, 256, 0, stream>>>(row_start, srcs, escore, xlh, bias1, C);

    // ---- pool + head (fused) ----
    pool_head_kernel<<<G_GRAPHS, 256, 0, stream>>>(C, batch, fc1w, fc1b, fc2w, fc2b, (float*)d_out);
}

// Round 12
// 393.785 us; speedup vs baseline: 1.1134x; 1.0346x over previous
//
#include <hip/hip_runtime.h>
#include <hip/hip_fp16.h>

#define N_NODES 50000
#define N_EDGES 1600000
#define H 64
#define IN_CH 7
#define EDIM 4
#define G_GRAPHS 256
#define FC 128
#define NC 2
#define SLOPE 0.2f
#define BSH 6                           // bucket shift: 64 nodes per bucket
#define BNODES 64
#define NBUCK ((N_NODES + BNODES - 1) / BNODES)    // 782
#define EPB1 8192                       // edges per front hist block
#define NB1 ((N_EDGES + EPB1 - 1) / EPB1)          // 196
#define PAIR_BLOCKS ((N_NODES * 32 + 255) / 256)   // 6250

typedef _Float16 h2v __attribute__((ext_vector_type(2)));

__device__ __forceinline__ float fdot2f(h2v a, h2v b, float c) {
#if defined(__has_builtin) && __has_builtin(__builtin_amdgcn_fdot2)
    return __builtin_amdgcn_fdot2(a, b, c, false);
#else
    return c + (float)a[0] * (float)b[0] + (float)a[1] * (float)b[1];
#endif
}

// ---------------- DPP wave-64 reductions ----------------
__device__ __forceinline__ float wave_sum_to63(float x) {
    x += __int_as_float(__builtin_amdgcn_update_dpp(0, __float_as_int(x), 0x111, 0xf, 0xf, true)); // row_shr:1
    x += __int_as_float(__builtin_amdgcn_update_dpp(0, __float_as_int(x), 0x112, 0xf, 0xf, true)); // row_shr:2
    x += __int_as_float(__builtin_amdgcn_update_dpp(0, __float_as_int(x), 0x114, 0xf, 0xf, true)); // row_shr:4
    x += __int_as_float(__builtin_amdgcn_update_dpp(0, __float_as_int(x), 0x118, 0xf, 0xf, true)); // row_shr:8
    x += __int_as_float(__builtin_amdgcn_update_dpp(0, __float_as_int(x), 0x142, 0xf, 0xf, true)); // row_bcast:15
    x += __int_as_float(__builtin_amdgcn_update_dpp(0, __float_as_int(x), 0x143, 0xf, 0xf, true)); // row_bcast:31
    return x;
}
__device__ __forceinline__ float lane63_bcast(float x) {
    return __int_as_float(__builtin_amdgcn_readlane(__float_as_int(x), 63));
}

// per-edge GATv2 score, packed fp16
__device__ __forceinline__ float gat_score(int4 ent,
        const __half2* __restrict__ xlh, const __half2* __restrict__ xrh,
        const __half2* __restrict__ weh, const __half2* __restrict__ atth) {
    __half2 ea01 = *reinterpret_cast<__half2*>(&ent.y);
    __half2 ea23 = *reinterpret_cast<__half2*>(&ent.z);
    __half2 e0 = __half2half2(__low2half(ea01));
    __half2 e1 = __half2half2(__high2half(ea01));
    __half2 e2 = __half2half2(__low2half(ea23));
    __half2 e3 = __half2half2(__high2half(ea23));
    const h2v sl = { (_Float16)SLOPE, (_Float16)SLOPE };
    const int4* xa = (const int4*)(xlh + (size_t)ent.x * 32);
    const int4* xb = (const int4*)(xrh + (size_t)ent.w * 32);
    float acc0 = 0.f, acc1 = 0.f;
#pragma unroll
    for (int k = 0; k < 8; ++k) {
        int4 va = xa[k];
        int4 vb = xb[k];
        const __half2* ha = reinterpret_cast<const __half2*>(&va);
        const __half2* hc = reinterpret_cast<const __half2*>(&vb);
#pragma unroll
        for (int j = 0; j < 4; ++j) {
            int c = k * 4 + j;                     // uniform -> scalar weight loads
            __half2 v2 = __hadd2(ha[j], hc[j]);
            v2 = __hfma2(e0, weh[c * 4 + 0], v2);
            v2 = __hfma2(e1, weh[c * 4 + 1], v2);
            v2 = __hfma2(e2, weh[c * 4 + 2], v2);
            v2 = __hfma2(e3, weh[c * 4 + 3], v2);
            h2v vv = *reinterpret_cast<h2v*>(&v2);
            h2v Lv = __builtin_elementwise_max(vv, sl * vv);   // v_pk_max_f16 leaky-relu
            __half2 av = atth[c];
            if (j & 1)
                acc1 = fdot2f(Lv, *reinterpret_cast<h2v*>(&av), acc1);
            else
                acc0 = fdot2f(Lv, *reinterpret_cast<h2v*>(&av), acc0);
        }
    }
    return acc0 + acc1;
}

// ---------------- fused front-end: coarse histogram+rank (LDS atomics) + proj0 + prep ----------------
__global__ __launch_bounds__(256) void front_kernel(
        const int* __restrict__ dst, int* __restrict__ rank1, int* __restrict__ bhist,
        const float* __restrict__ xin,
        const float* __restrict__ Wl0, const float* __restrict__ bl0,
        const float* __restrict__ Wr0, const float* __restrict__ br0,
        __half2* __restrict__ xlh, __half2* __restrict__ xrh,
        const float* __restrict__ We0, const float* __restrict__ We1,
        const float* __restrict__ Wl1, const float* __restrict__ bl1,
        const float* __restrict__ Wr1, const float* __restrict__ br1,
        __half2* __restrict__ weh0, __half2* __restrict__ weh1,
        __half2* __restrict__ wt, float* __restrict__ bb,
        const float* __restrict__ att0, const float* __restrict__ att1,
        __half2* __restrict__ atth0, __half2* __restrict__ atth1) {
    __shared__ int hist[NBUCK];
    int b = blockIdx.x;
    int t = threadIdx.x;
    if (b < NB1) {
        for (int i = t; i < NBUCK; i += 256) hist[i] = 0;
        __syncthreads();
#pragma unroll
        for (int i = 0; i < EPB1 / 256; ++i) {
            int e = b * EPB1 + i * 256 + t;
            if (e < N_EDGES) {
                int k = dst[e] >> BSH;
                rank1[e] = atomicAdd(&hist[k], 1);
            }
        }
        __syncthreads();
        for (int i = t; i < NBUCK; i += 256) bhist[b * NBUCK + i] = hist[i];
    } else if (b < NB1 + PAIR_BLOCKS) {
        int idx = (b - NB1) * 256 + t;
        if (idx < N_NODES * 32) {
            int n = idx >> 5;
            int c = idx & 31;
            const float* xi = xin + n * IN_CH;
            float2 bl2 = ((const float2*)bl0)[c];
            float2 br2 = ((const float2*)br0)[c];
            float al0 = bl2.x, al1 = bl2.y, ar0 = br2.x, ar1 = br2.y;
#pragma unroll
            for (int k = 0; k < IN_CH; ++k) {
                float xv = xi[k];
                float2 wl2 = ((const float2*)(Wl0 + k * H))[c];
                float2 wr2 = ((const float2*)(Wr0 + k * H))[c];
                al0 += xv * wl2.x; al1 += xv * wl2.y;
                ar0 += xv * wr2.x; ar1 += xv * wr2.y;
            }
            xlh[idx] = __floats2half2_rn(al0, al1);
            xrh[idx] = __floats2half2_rn(ar0, ar1);
        }
    } else {
        if (t < 32) {
            for (int k = 0; k < 4; ++k)
                weh0[t * 4 + k] = __floats2half2_rn(We0[k * H + 2 * t], We0[k * H + 2 * t + 1]);
        } else if (t < 64) {
            int c = t - 32;
            for (int k = 0; k < 4; ++k)
                weh1[c * 4 + k] = __floats2half2_rn(We1[k * H + 2 * c], We1[k * H + 2 * c + 1]);
        }
        if (t < 128) {
            const float* W = (t < 64) ? Wl1 : Wr1;
            int c = t & 63;
            for (int kk = 0; kk < 32; ++kk)
                wt[t * 32 + kk] = __floats2half2_rn(W[(2 * kk) * H + c], W[(2 * kk + 1) * H + c]);
            bb[t] = (t < 64) ? bl1[c] : br1[c];
        } else if (t < 160) {
            int c = t - 128;
            atth0[c] = __floats2half2_rn(att0[2 * c], att0[2 * c + 1]);
            atth1[c] = __floats2half2_rn(att1[2 * c], att1[2 * c + 1]);
        }
    }
}

// scan A: one block per bucket k; exclusive scan of bhist[b][k] over the 196 front
// blocks -> bases[b][k], total -> btot[k]. All buckets in parallel.
__global__ __launch_bounds__(256) void scan_a_kernel(
        const int* __restrict__ bhist, int* __restrict__ bases, int* __restrict__ btot) {
    __shared__ int lds[256];
    int k = blockIdx.x;
    int t = threadIdx.x;
    int v = (t < NB1) ? bhist[t * NBUCK + k] : 0;
    lds[t] = v;
    __syncthreads();
    for (int off = 1; off < 256; off <<= 1) {
        int x = (t >= off) ? lds[t - off] : 0;
        __syncthreads();
        lds[t] += x;
        __syncthreads();
    }
    if (t < NB1) bases[t * NBUCK + k] = lds[t] - v;
    if (t == NB1 - 1) btot[k] = lds[t];
}

// scan B: single block, exclusive scan of 782 bucket totals -> cb_start.
__global__ __launch_bounds__(1024) void scan_b_kernel(
        const int* __restrict__ btot, int* __restrict__ cb_start) {
    __shared__ int lds[1024];
    int t = threadIdx.x;
    int v = (t < NBUCK) ? btot[t] : 0;
    lds[t] = v;
    __syncthreads();
    for (int off = 1; off < 1024; off <<= 1) {
        int x = (t >= off) ? lds[t - off] : 0;
        __syncthreads();
        lds[t] += x;
        __syncthreads();
    }
    if (t < NBUCK) cb_start[t] = lds[t] - v;
    if (t == NBUCK - 1) cb_start[NBUCK] = lds[t];
}

// coarse scatter: edge -> bucket-sorted tmp (block-sequential slots within bucket)
__global__ void coarse_scatter_kernel(const int* __restrict__ src, const int* __restrict__ dst,
                                      const int* __restrict__ rank1, const int* __restrict__ bases,
                                      const int* __restrict__ cb_start,
                                      const float* __restrict__ edge_attr,
                                      int4* __restrict__ tmp) {
    int e = blockIdx.x * blockDim.x + threadIdx.x;
    if (e >= N_EDGES) return;
    int d = dst[e];
    int k = d >> BSH;
    int b = e / EPB1;
    int slot = cb_start[k] + bases[b * NBUCK + k] + rank1[e];
    float4 ea = ((const float4*)edge_attr)[e];
    __half2 h01 = __floats2half2_rn(ea.x, ea.y);
    __half2 h23 = __floats2half2_rn(ea.z, ea.w);
    int4 ent;
    ent.x = src[e];
    ent.y = *reinterpret_cast<int*>(&h01);
    ent.z = *reinterpret_cast<int*>(&h23);
    ent.w = d;
    tmp[slot] = ent;
}

// fine sort: one block per 64-node bucket (782 blocks); emits csr + srcs + row_start.
__global__ __launch_bounds__(256) void fine_sort_kernel(
        const int* __restrict__ cb_start, const int4* __restrict__ tmp,
        int4* __restrict__ csr, int* __restrict__ srcs,
        int* __restrict__ row_start) {
    __shared__ int hist2[BNODES];
    __shared__ int cursor[BNODES];
    __shared__ int lds[BNODES];
    int k = blockIdx.x;
    int t = threadIdx.x;
    int beg = cb_start[k], end = cb_start[k + 1];
    if (t < BNODES) hist2[t] = 0;
    __syncthreads();
    for (int i = beg + t; i < end; i += 256)
        atomicAdd(&hist2[tmp[i].w & (BNODES - 1)], 1);
    __syncthreads();
    int v = 0;
    if (t < BNODES) { v = hist2[t]; lds[t] = v; }
    __syncthreads();
    for (int off = 1; off < BNODES; off <<= 1) {
        int x = (t < BNODES && t >= off) ? lds[t - off] : 0;
        __syncthreads();
        if (t < BNODES) lds[t] += x;
        __syncthreads();
    }
    if (t < BNODES) {
        int pre = lds[t] - v;
        cursor[t] = pre;
        int node = (k << BSH) + t;
        if (node <= N_NODES) row_start[node] = beg + pre;
    }
    __syncthreads();
    for (int i = beg + t; i < end; i += 256) {
        int4 ent = tmp[i];
        int slot = beg + atomicAdd(&cursor[ent.w & (BNODES - 1)], 1);
        csr[slot] = ent;
        srcs[slot] = ent.x;
    }
}

// ---------------- layer-1 projection: lane = node, scalar weights ----------------
__global__ __launch_bounds__(256) void proj1_kernel(
        const float* __restrict__ xin,
        const __half2* __restrict__ wt,
        const float* __restrict__ bb,
        __half2* __restrict__ xlh, __half2* __restrict__ xrh) {
    int g = __builtin_amdgcn_readfirstlane((int)(threadIdx.x >> 6));
    int lane = threadIdx.x & 63;
    int node = blockIdx.x * 64 + lane;
    if (node >= N_NODES) return;

    h2v xrow[32];
    const float4* xp = (const float4*)(xin + node * 64);
#pragma unroll
    for (int q = 0; q < 16; ++q) {
        float4 v = xp[q];
        __half2 a = __floats2half2_rn(v.x, v.y);
        __half2 b = __floats2half2_rn(v.z, v.w);
        xrow[2 * q]     = *reinterpret_cast<h2v*>(&a);
        xrow[2 * q + 1] = *reinterpret_cast<h2v*>(&b);
    }

    __half2* outp = (g < 2) ? xlh : xrh;
    int chbase = g * 32;
    int localbase = (g & 1) * 16;

#pragma unroll
    for (int cp = 0; cp < 16; ++cp) {
        int ch0 = chbase + 2 * cp;
        const h2v* w0 = (const h2v*)(wt + ch0 * 32);
        const h2v* w1 = (const h2v*)(wt + (ch0 + 1) * 32);
        float a0 = bb[ch0], a1 = bb[ch0 + 1];
#pragma unroll
        for (int kk = 0; kk < 32; ++kk) {
            a0 = fdot2f(xrow[kk], w0[kk], a0);
            a1 = fdot2f(xrow[kk], w1[kk], a1);
        }
        outp[node * 32 + localbase + cp] = __floats2half2_rn(a0, a1);
    }
}

// ---------------- per-edge score over csr ----------------
__global__ __launch_bounds__(256) void score_kernel(
        const int4* __restrict__ csr,
        const __half2* __restrict__ xlh, const __half2* __restrict__ xrh,
        const __half2* __restrict__ weh, const __half2* __restrict__ atth,
        float* __restrict__ score) {
    int e = blockIdx.x * 256 + threadIdx.x;
    score[e] = gat_score(csr[e], xlh, xrh, weh, atth);
}

// ---------------- aggregation v2: one wave per node, 16 lanes per edge ----------------
// lane&15 = channel quad (int2 = 4 ch, 8B load); lane>>4 = edge subgroup -> 4 edges
// processed in parallel per wave iteration. (src,p) via one vector load per 64-edge
// chunk + ds_bpermute broadcast, replacing scalar-load/readlane/cndmask chains.
__global__ __launch_bounds__(256) void agg_kernel(
        const int* __restrict__ row_start,
        const int* __restrict__ srcs,
        const float* __restrict__ score,
        const __half2* __restrict__ xlh,
        const float* __restrict__ bias,
        float* __restrict__ out) {
    int wave = (blockIdx.x * blockDim.x + threadIdx.x) >> 6;
    if (wave >= N_NODES) return;
    int lane = threadIdx.x & 63;
    int q = lane & 15;            // channel quad: ch 4q..4q+3
    int grp = lane >> 4;          // edge subgroup 0..3
    int d = wave;
    int beg = __builtin_amdgcn_readfirstlane(row_start[d]);
    int end = __builtin_amdgcn_readfirstlane(row_start[d + 1]);

    const int2* xl2 = (const int2*)xlh;   // row = 16 int2 (4 ch each)

    float l_lane = 0.f;
    float a0 = 0.f, a1 = 0.f, a2 = 0.f, a3 = 0.f;

    for (int cbeg = beg; cbeg < end; cbeg += 64) {
        int n = end - cbeg;
        int nn = min(n, 64);
        // per-lane score + src (overreads land in mapped pad / following arrays)
        float sc = score[cbeg + lane];
        float p = __expf(sc);
        p = (lane < n) ? p : 0.f;
        l_lane += p;
        int sv = srcs[cbeg + lane];

        for (int j = 0; j < nn; j += 4) {
            int e = j + grp;
            bool ok = e < nn;
            int esel = ok ? e : 0;
            int s = __shfl(sv, esel, 64);          // ds_bpermute
            float pe = __shfl(p, esel, 64);
            pe = ok ? pe : 0.f;                    // zero contribution for tail groups
            int2 xw = xl2[(size_t)s * 16 + q];
            __half2 h0 = *reinterpret_cast<__half2*>(&xw.x);
            __half2 h1 = *reinterpret_cast<__half2*>(&xw.y);
            float2 f0 = __half22float2(h0);
            float2 f1 = __half22float2(h1);
            a0 += pe * f0.x; a1 += pe * f0.y;
            a2 += pe * f1.x; a3 += pe * f1.y;
        }
    }

    // reduce across the 4 edge subgroups (lane bits 4,5)
    a0 += __shfl_xor(a0, 16, 64); a0 += __shfl_xor(a0, 32, 64);
    a1 += __shfl_xor(a1, 16, 64); a1 += __shfl_xor(a1, 32, 64);
    a2 += __shfl_xor(a2, 16, 64); a2 += __shfl_xor(a2, 32, 64);
    a3 += __shfl_xor(a3, 16, 64); a3 += __shfl_xor(a3, 32, 64);
    float l = lane63_bcast(wave_sum_to63(l_lane));
    if (grp == 0) {
        float inv = 1.f / (l + 1e-16f);
        float4 b4 = ((const float4*)bias)[q];
        float o0 = a0 * inv + b4.x;
        float o1 = a1 * inv + b4.y;
        float o2 = a2 * inv + b4.z;
        float o3 = a3 * inv + b4.w;
        o0 = o0 > 0.f ? o0 : expm1f(o0);
        o1 = o1 > 0.f ? o1 : expm1f(o1);
        o2 = o2 > 0.f ? o2 : expm1f(o2);
        o3 = o3 > 0.f ? o3 : expm1f(o3);
        ((float4*)out)[d * 16 + q] = float4{o0, o1, o2, o3};
    }
}

// ---------------- fused pool + head: one block per graph ----------------
__global__ __launch_bounds__(256) void pool_head_kernel(
        const float* __restrict__ h, const int* __restrict__ batch,
        const float* __restrict__ fc1w, const float* __restrict__ fc1b,
        const float* __restrict__ fc2w, const float* __restrict__ fc2b,
        float* __restrict__ out) {
    int g = blockIdx.x;
    int lo = 0, hi = N_NODES;
    while (lo < hi) { int mid = (lo + hi) >> 1; if (batch[mid] < g) lo = mid + 1; else hi = mid; }
    int start = lo;
    hi = N_NODES;
    while (lo < hi) { int mid = (lo + hi) >> 1; if (batch[mid] < g + 1) lo = mid + 1; else hi = mid; }
    int end = lo;

    int lane = threadIdx.x & 63;
    int w = threadIdx.x >> 6;
    float s = 0.f;
    for (int n = start + w; n < end; n += 4) s += h[n * H + lane];
    __shared__ float red[4][H];
    __shared__ float gv[H];
    __shared__ float f[FC];
    __shared__ float lg[NC];
    red[w][lane] = s;
    __syncthreads();
    if (w == 0) {
        float tot = red[0][lane] + red[1][lane] + red[2][lane] + red[3][lane];
        gv[lane] = tot / fmaxf((float)(end - start), 1.f);
    }
    __syncthreads();
    int t = threadIdx.x;
    if (t < FC) {
        float acc = fc1b[t];
#pragma unroll 16
        for (int k = 0; k < H; ++k) acc += gv[k] * fc1w[k * FC + t];
        f[t] = fmaxf(acc, 0.f);
    }
    __syncthreads();
    if (t < NC) {
        float a = fc2b[t];
        for (int k = 0; k < FC; ++k) a += f[k] * fc2w[k * NC + t];
        lg[t] = a;
    }
    __syncthreads();
    if (t < NC) {
        float mx = fmaxf(lg[0], lg[1]);
        float lse = mx + logf(expf(lg[0] - mx) + expf(lg[1] - mx));
        out[g * NC + t] = lg[t] - lse;
    }
}

extern "C" void kernel_launch(void* const* d_in, const int* in_sizes, int n_in,
                              void* d_out, int out_size, void* d_ws, size_t ws_size,
                              hipStream_t stream) {
    const float* x         = (const float*)d_in[0];
    const int*   edge_idx  = (const int*)d_in[1];
    const float* edge_attr = (const float*)d_in[2];
    const int*   batch     = (const int*)d_in[3];
    const float* Wl0  = (const float*)d_in[4];
    const float* bl0  = (const float*)d_in[5];
    const float* Wr0  = (const float*)d_in[6];
    const float* br0  = (const float*)d_in[7];
    const float* We0  = (const float*)d_in[8];
    const float* att0 = (const float*)d_in[9];
    const float* bias0= (const float*)d_in[10];
    const float* Wl1  = (const float*)d_in[11];
    const float* bl1  = (const float*)d_in[12];
    const float* Wr1  = (const float*)d_in[13];
    const float* br1  = (const float*)d_in[14];
    const float* We1  = (const float*)d_in[15];
    const float* att1 = (const float*)d_in[16];
    const float* bias1= (const float*)d_in[17];
    const float* fc1w = (const float*)d_in[18];
    const float* fc1b = (const float*)d_in[19];
    const float* fc2w = (const float*)d_in[20];
    const float* fc2b = (const float*)d_in[21];

    // ---- workspace layout ----
    // tmp aliases [C | escore | pad] (tmp dead after fine_sort; C/escore written after).
    __half2* xlh    = (__half2*)d_ws;                 // [N*32]
    __half2* xrh    = xlh + N_NODES * 32;             // [N*32]
    float* C        = (float*)(xrh + N_NODES * 32);   // [N,64] fp32 ┐
    float* escore   = C + N_NODES * 64;               // [E]         ├ tmp aliases these
    float* pad      = escore + N_EDGES;               // [E]         ┘
    int4*  tmp      = (int4*)C;                       // [E]
    int4*  csr      = (int4*)(pad + N_EDGES);         // [E]
    int*   srcs     = (int*)(csr + N_EDGES);          // [E]
    int*   row_start= srcs + N_EDGES;                 // [N+1]
    int*   rank1    = row_start + N_NODES + 1;        // [E]
    int*   bhist    = rank1 + N_EDGES;                // [NB1*NBUCK]
    int*   bases    = bhist + NB1 * NBUCK;            // [NB1*NBUCK]
    int*   btot     = bases + NB1 * NBUCK;            // [NBUCK]
    int*   cb_start = btot + NBUCK;                   // [NBUCK+1]
    __half2* weh0   = (__half2*)(cb_start + NBUCK + 1);
    __half2* weh1   = weh0 + 128;
    __half2* wt1    = weh1 + 128;                     // [128*32]
    float* bb1      = (float*)(wt1 + 128 * 32);       // [128]
    __half2* atth0  = (__half2*)(bb1 + 128);          // [32]
    __half2* atth1  = atth0 + 32;                     // [32]

    const int* src = edge_idx;
    const int* dst = edge_idx + N_EDGES;

    const int edgeBlocks  = (N_EDGES + 255) / 256;
    const int waveBlocks  = (N_NODES * 64 + 255) / 256;
    const int p1Blocks    = (N_NODES + 63) / 64;
    const int frontBlocks = NB1 + PAIR_BLOCKS + 1;

    // ---- CSR build via 2-pass radix (LDS atomics, parallel scans) + proj0 + prep ----
    front_kernel<<<frontBlocks, 256, 0, stream>>>(dst, rank1, bhist,
                                                  x, Wl0, bl0, Wr0, br0, xlh, xrh,
                                                  We0, We1, Wl1, bl1, Wr1, br1,
                                                  weh0, weh1, wt1, bb1,
                                                  att0, att1, atth0, atth1);
    scan_a_kernel<<<NBUCK, 256, 0, stream>>>(bhist, bases, btot);
    scan_b_kernel<<<1, 1024, 0, stream>>>(btot, cb_start);
    coarse_scatter_kernel<<<edgeBlocks, 256, 0, stream>>>(src, dst, rank1, bases, cb_start,
                                                          edge_attr, tmp);
    fine_sort_kernel<<<NBUCK, 256, 0, stream>>>(cb_start, tmp, csr, srcs, row_start);

    // ---- layer 0 ----
    score_kernel<<<edgeBlocks, 256, 0, stream>>>(csr, xlh, xrh, weh0, atth0, escore);
    agg_kernel<<<waveBlocks, 256, 0, stream>>>(row_start, srcs, escore, xlh, bias0, C);

    // ---- layer 1 ----
    proj1_kernel<<<p1Blocks, 256, 0, stream>>>(C, wt1, bb1, xlh, xrh);
    score_kernel<<<edgeBlocks, 256, 0, stream>>>(csr, xlh, xrh, weh1, atth1, escore);
    agg_kernel<<<waveBlocks, 256, 0, stream>>>(row_start, srcs, escore, xlh, bias1, C);

    // ---- pool + head (fused) ----
    pool_head_kernel<<<G_GRAPHS, 256, 0, stream>>>(C, batch, fc1w, fc1b, fc2w, fc2b, (float*)d_out);
}

// Round 13
// 379.766 us; speedup vs baseline: 1.1545x; 1.0369x over previous
//
#include <hip/hip_runtime.h>
#include <hip/hip_fp16.h>

#define N_NODES 50000
#define N_EDGES 1600000
#define H 64
#define IN_CH 7
#define EDIM 4
#define G_GRAPHS 256
#define FC 128
#define NC 2
#define SLOPE 0.2f
#define BSH 6                           // bucket shift: 64 nodes per bucket
#define BNODES 64
#define NBUCK ((N_NODES + BNODES - 1) / BNODES)    // 782
#define EPB1 8192                       // edges per front hist block
#define NB1 ((N_EDGES + EPB1 - 1) / EPB1)          // 196
#define PAIR_BLOCKS ((N_NODES * 32 + 255) / 256)   // 6250

typedef _Float16 h2v __attribute__((ext_vector_type(2)));

__device__ __forceinline__ float fdot2f(h2v a, h2v b, float c) {
#if defined(__has_builtin) && __has_builtin(__builtin_amdgcn_fdot2)
    return __builtin_amdgcn_fdot2(a, b, c, false);
#else
    return c + (float)a[0] * (float)b[0] + (float)a[1] * (float)b[1];
#endif
}

// ---------------- DPP wave-64 reductions ----------------
__device__ __forceinline__ float wave_sum_to63(float x) {
    x += __int_as_float(__builtin_amdgcn_update_dpp(0, __float_as_int(x), 0x111, 0xf, 0xf, true)); // row_shr:1
    x += __int_as_float(__builtin_amdgcn_update_dpp(0, __float_as_int(x), 0x112, 0xf, 0xf, true)); // row_shr:2
    x += __int_as_float(__builtin_amdgcn_update_dpp(0, __float_as_int(x), 0x114, 0xf, 0xf, true)); // row_shr:4
    x += __int_as_float(__builtin_amdgcn_update_dpp(0, __float_as_int(x), 0x118, 0xf, 0xf, true)); // row_shr:8
    x += __int_as_float(__builtin_amdgcn_update_dpp(0, __float_as_int(x), 0x142, 0xf, 0xf, true)); // row_bcast:15
    x += __int_as_float(__builtin_amdgcn_update_dpp(0, __float_as_int(x), 0x143, 0xf, 0xf, true)); // row_bcast:31
    return x;
}
__device__ __forceinline__ float lane63_bcast(float x) {
    return __int_as_float(__builtin_amdgcn_readlane(__float_as_int(x), 63));
}

// ---------------- fused front-end: coarse histogram+rank (LDS atomics) + proj0 + prep ----------------
__global__ __launch_bounds__(256) void front_kernel(
        const int* __restrict__ dst, int* __restrict__ rank1, int* __restrict__ bhist,
        const float* __restrict__ xin,
        const float* __restrict__ Wl0, const float* __restrict__ bl0,
        const float* __restrict__ Wr0, const float* __restrict__ br0,
        __half2* __restrict__ xlh, __half2* __restrict__ xrh,
        const float* __restrict__ We0, const float* __restrict__ We1,
        const float* __restrict__ Wl1, const float* __restrict__ bl1,
        const float* __restrict__ Wr1, const float* __restrict__ br1,
        __half2* __restrict__ weh0, __half2* __restrict__ weh1,
        __half2* __restrict__ wt, float* __restrict__ bb,
        const float* __restrict__ att0, const float* __restrict__ att1,
        __half2* __restrict__ atth0, __half2* __restrict__ atth1) {
    __shared__ int hist[NBUCK];
    int b = blockIdx.x;
    int t = threadIdx.x;
    if (b < NB1) {
        for (int i = t; i < NBUCK; i += 256) hist[i] = 0;
        __syncthreads();
#pragma unroll
        for (int i = 0; i < EPB1 / 256; ++i) {
            int e = b * EPB1 + i * 256 + t;
            if (e < N_EDGES) {
                int k = dst[e] >> BSH;
                rank1[e] = atomicAdd(&hist[k], 1);
            }
        }
        __syncthreads();
        for (int i = t; i < NBUCK; i += 256) bhist[b * NBUCK + i] = hist[i];
    } else if (b < NB1 + PAIR_BLOCKS) {
        int idx = (b - NB1) * 256 + t;
        if (idx < N_NODES * 32) {
            int n = idx >> 5;
            int c = idx & 31;
            const float* xi = xin + n * IN_CH;
            float2 bl2 = ((const float2*)bl0)[c];
            float2 br2 = ((const float2*)br0)[c];
            float al0 = bl2.x, al1 = bl2.y, ar0 = br2.x, ar1 = br2.y;
#pragma unroll
            for (int k = 0; k < IN_CH; ++k) {
                float xv = xi[k];
                float2 wl2 = ((const float2*)(Wl0 + k * H))[c];
                float2 wr2 = ((const float2*)(Wr0 + k * H))[c];
                al0 += xv * wl2.x; al1 += xv * wl2.y;
                ar0 += xv * wr2.x; ar1 += xv * wr2.y;
            }
            xlh[idx] = __floats2half2_rn(al0, al1);
            xrh[idx] = __floats2half2_rn(ar0, ar1);
        }
    } else {
        if (t < 32) {
            for (int k = 0; k < 4; ++k)
                weh0[t * 4 + k] = __floats2half2_rn(We0[k * H + 2 * t], We0[k * H + 2 * t + 1]);
        } else if (t < 64) {
            int c = t - 32;
            for (int k = 0; k < 4; ++k)
                weh1[c * 4 + k] = __floats2half2_rn(We1[k * H + 2 * c], We1[k * H + 2 * c + 1]);
        }
        if (t < 128) {
            const float* W = (t < 64) ? Wl1 : Wr1;
            int c = t & 63;
            for (int kk = 0; kk < 32; ++kk)
                wt[t * 32 + kk] = __floats2half2_rn(W[(2 * kk) * H + c], W[(2 * kk + 1) * H + c]);
            bb[t] = (t < 64) ? bl1[c] : br1[c];
        } else if (t < 160) {
            int c = t - 128;
            atth0[c] = __floats2half2_rn(att0[2 * c], att0[2 * c + 1]);
            atth1[c] = __floats2half2_rn(att1[2 * c], att1[2 * c + 1]);
        }
    }
}

// scan A: one block per bucket k; exclusive scan of bhist[b][k] over the 196 front
// blocks -> bases[b][k], total -> btot[k]. All buckets in parallel.
__global__ __launch_bounds__(256) void scan_a_kernel(
        const int* __restrict__ bhist, int* __restrict__ bases, int* __restrict__ btot) {
    __shared__ int lds[256];
    int k = blockIdx.x;
    int t = threadIdx.x;
    int v = (t < NB1) ? bhist[t * NBUCK + k] : 0;
    lds[t] = v;
    __syncthreads();
    for (int off = 1; off < 256; off <<= 1) {
        int x = (t >= off) ? lds[t - off] : 0;
        __syncthreads();
        lds[t] += x;
        __syncthreads();
    }
    if (t < NB1) bases[t * NBUCK + k] = lds[t] - v;
    if (t == NB1 - 1) btot[k] = lds[t];
}

// scan B: single block, exclusive scan of 782 bucket totals -> cb_start.
__global__ __launch_bounds__(1024) void scan_b_kernel(
        const int* __restrict__ btot, int* __restrict__ cb_start) {
    __shared__ int lds[1024];
    int t = threadIdx.x;
    int v = (t < NBUCK) ? btot[t] : 0;
    lds[t] = v;
    __syncthreads();
    for (int off = 1; off < 1024; off <<= 1) {
        int x = (t >= off) ? lds[t - off] : 0;
        __syncthreads();
        lds[t] += x;
        __syncthreads();
    }
    if (t < NBUCK) cb_start[t] = lds[t] - v;
    if (t == NBUCK - 1) cb_start[NBUCK] = lds[t];
}

// coarse scatter: edge -> bucket-sorted tmp (block-sequential slots within bucket)
__global__ void coarse_scatter_kernel(const int* __restrict__ src, const int* __restrict__ dst,
                                      const int* __restrict__ rank1, const int* __restrict__ bases,
                                      const int* __restrict__ cb_start,
                                      const float* __restrict__ edge_attr,
                                      int4* __restrict__ tmp) {
    int e = blockIdx.x * blockDim.x + threadIdx.x;
    if (e >= N_EDGES) return;
    int d = dst[e];
    int k = d >> BSH;
    int b = e / EPB1;
    int slot = cb_start[k] + bases[b * NBUCK + k] + rank1[e];
    float4 ea = ((const float4*)edge_attr)[e];
    __half2 h01 = __floats2half2_rn(ea.x, ea.y);
    __half2 h23 = __floats2half2_rn(ea.z, ea.w);
    int4 ent;
    ent.x = src[e];
    ent.y = *reinterpret_cast<int*>(&h01);
    ent.z = *reinterpret_cast<int*>(&h23);
    ent.w = d;
    tmp[slot] = ent;
}

// fine sort: one block per 64-node bucket (782 blocks); emits csr + srcs + row_start.
__global__ __launch_bounds__(256) void fine_sort_kernel(
        const int* __restrict__ cb_start, const int4* __restrict__ tmp,
        int4* __restrict__ csr, int* __restrict__ srcs,
        int* __restrict__ row_start) {
    __shared__ int hist2[BNODES];
    __shared__ int cursor[BNODES];
    __shared__ int lds[BNODES];
    int k = blockIdx.x;
    int t = threadIdx.x;
    int beg = cb_start[k], end = cb_start[k + 1];
    if (t < BNODES) hist2[t] = 0;
    __syncthreads();
    for (int i = beg + t; i < end; i += 256)
        atomicAdd(&hist2[tmp[i].w & (BNODES - 1)], 1);
    __syncthreads();
    int v = 0;
    if (t < BNODES) { v = hist2[t]; lds[t] = v; }
    __syncthreads();
    for (int off = 1; off < BNODES; off <<= 1) {
        int x = (t < BNODES && t >= off) ? lds[t - off] : 0;
        __syncthreads();
        if (t < BNODES) lds[t] += x;
        __syncthreads();
    }
    if (t < BNODES) {
        int pre = lds[t] - v;
        cursor[t] = pre;
        int node = (k << BSH) + t;
        if (node <= N_NODES) row_start[node] = beg + pre;
    }
    __syncthreads();
    for (int i = beg + t; i < end; i += 256) {
        int4 ent = tmp[i];
        int slot = beg + atomicAdd(&cursor[ent.w & (BNODES - 1)], 1);
        csr[slot] = ent;
        srcs[slot] = ent.x;
    }
}

// ---------------- layer-1 projection: lane = node, scalar weights ----------------
__global__ __launch_bounds__(256) void proj1_kernel(
        const float* __restrict__ xin,
        const __half2* __restrict__ wt,
        const float* __restrict__ bb,
        __half2* __restrict__ xlh, __half2* __restrict__ xrh) {
    int g = __builtin_amdgcn_readfirstlane((int)(threadIdx.x >> 6));
    int lane = threadIdx.x & 63;
    int node = blockIdx.x * 64 + lane;
    if (node >= N_NODES) return;

    h2v xrow[32];
    const float4* xp = (const float4*)(xin + node * 64);
#pragma unroll
    for (int q = 0; q < 16; ++q) {
        float4 v = xp[q];
        __half2 a = __floats2half2_rn(v.x, v.y);
        __half2 b = __floats2half2_rn(v.z, v.w);
        xrow[2 * q]     = *reinterpret_cast<h2v*>(&a);
        xrow[2 * q + 1] = *reinterpret_cast<h2v*>(&b);
    }

    __half2* outp = (g < 2) ? xlh : xrh;
    int chbase = g * 32;
    int localbase = (g & 1) * 16;

#pragma unroll
    for (int cp = 0; cp < 16; ++cp) {
        int ch0 = chbase + 2 * cp;
        const h2v* w0 = (const h2v*)(wt + ch0 * 32);
        const h2v* w1 = (const h2v*)(wt + (ch0 + 1) * 32);
        float a0 = bb[ch0], a1 = bb[ch0 + 1];
#pragma unroll
        for (int kk = 0; kk < 32; ++kk) {
            a0 = fdot2f(xrow[kk], w0[kk], a0);
            a1 = fdot2f(xrow[kk], w1[kk], a1);
        }
        outp[node * 32 + localbase + cp] = __floats2half2_rn(a0, a1);
    }
}

// ---------------- per-edge score: 4 lanes per edge (quarter-row cooperative gather) ----------------
// Lane group of 4 loads the same csr entry (L1-merged) and each lane 2x16B = 32B
// quarter-rows of xl/xr -> same-line requests merge in L1 (~5 unique-line lookups
// per edge vs 17 single-lane). Weight/att tables read from LDS (idle pipe).
__global__ __launch_bounds__(256) void score_kernel(
        const int4* __restrict__ csr,
        const __half2* __restrict__ xlh, const __half2* __restrict__ xrh,
        const __half2* __restrict__ weh, const __half2* __restrict__ atth,
        float* __restrict__ score) {
    __shared__ __half2 sweh[128];
    __shared__ __half2 satth[32];
    int t = threadIdx.x;
    if (t < 128) sweh[t] = weh[t];
    else if (t < 160) satth[t - 128] = atth[t - 128];
    __syncthreads();

    int e = blockIdx.x * 64 + (t >> 2);   // N_EDGES % 64 == 0
    int sub = t & 3;                      // channel chunk: half2 indices sub*8..sub*8+7
    int4 ent = csr[e];
    __half2 ea01 = *reinterpret_cast<__half2*>(&ent.y);
    __half2 ea23 = *reinterpret_cast<__half2*>(&ent.z);
    __half2 e0 = __half2half2(__low2half(ea01));
    __half2 e1 = __half2half2(__high2half(ea01));
    __half2 e2 = __half2half2(__low2half(ea23));
    __half2 e3 = __half2half2(__high2half(ea23));
    const h2v sl = { (_Float16)SLOPE, (_Float16)SLOPE };

    const int4* xa = (const int4*)(xlh + (size_t)ent.x * 32) + sub * 2;
    const int4* xb = (const int4*)(xrh + (size_t)ent.w * 32) + sub * 2;
    int4 va[2], vb[2];
    va[0] = xa[0]; va[1] = xa[1];
    vb[0] = xb[0]; vb[1] = xb[1];
    const __half2* ha = reinterpret_cast<const __half2*>(va);
    const __half2* hc = reinterpret_cast<const __half2*>(vb);

    float acc = 0.f;
#pragma unroll
    for (int j = 0; j < 8; ++j) {
        int c = sub * 8 + j;
        __half2 v2 = __hadd2(ha[j], hc[j]);
        v2 = __hfma2(e0, sweh[c * 4 + 0], v2);
        v2 = __hfma2(e1, sweh[c * 4 + 1], v2);
        v2 = __hfma2(e2, sweh[c * 4 + 2], v2);
        v2 = __hfma2(e3, sweh[c * 4 + 3], v2);
        h2v vv = *reinterpret_cast<h2v*>(&v2);
        h2v Lv = __builtin_elementwise_max(vv, sl * vv);   // v_pk_max_f16 leaky-relu
        __half2 av = satth[c];
        acc = fdot2f(Lv, *reinterpret_cast<h2v*>(&av), acc);
    }
    acc += __shfl_xor(acc, 1, 64);
    acc += __shfl_xor(acc, 2, 64);
    if (sub == 0) score[e] = acc;
}

// ---------------- aggregation v2: one wave per node, 16 lanes per edge ----------------
// lane&15 = channel quad (int2 = 4 ch, 8B load); lane>>4 = edge subgroup -> 4 edges
// processed in parallel per wave iteration. (src,p) via one vector load per 64-edge
// chunk + ds_bpermute broadcast, replacing scalar-load/readlane/cndmask chains.
__global__ __launch_bounds__(256) void agg_kernel(
        const int* __restrict__ row_start,
        const int* __restrict__ srcs,
        const float* __restrict__ score,
        const __half2* __restrict__ xlh,
        const float* __restrict__ bias,
        float* __restrict__ out) {
    int wave = (blockIdx.x * blockDim.x + threadIdx.x) >> 6;
    if (wave >= N_NODES) return;
    int lane = threadIdx.x & 63;
    int q = lane & 15;            // channel quad: ch 4q..4q+3
    int grp = lane >> 4;          // edge subgroup 0..3
    int d = wave;
    int beg = __builtin_amdgcn_readfirstlane(row_start[d]);
    int end = __builtin_amdgcn_readfirstlane(row_start[d + 1]);

    const int2* xl2 = (const int2*)xlh;   // row = 16 int2 (4 ch each)

    float l_lane = 0.f;
    float a0 = 0.f, a1 = 0.f, a2 = 0.f, a3 = 0.f;

    for (int cbeg = beg; cbeg < end; cbeg += 64) {
        int n = end - cbeg;
        int nn = min(n, 64);
        // per-lane score + src (overreads land in mapped pad / following arrays)
        float sc = score[cbeg + lane];
        float p = __expf(sc);
        p = (lane < n) ? p : 0.f;
        l_lane += p;
        int sv = srcs[cbeg + lane];

        for (int j = 0; j < nn; j += 4) {
            int e = j + grp;
            bool ok = e < nn;
            int esel = ok ? e : 0;
            int s = __shfl(sv, esel, 64);          // ds_bpermute
            float pe = __shfl(p, esel, 64);
            pe = ok ? pe : 0.f;                    // zero contribution for tail groups
            int2 xw = xl2[(size_t)s * 16 + q];
            __half2 h0 = *reinterpret_cast<__half2*>(&xw.x);
            __half2 h1 = *reinterpret_cast<__half2*>(&xw.y);
            float2 f0 = __half22float2(h0);
            float2 f1 = __half22float2(h1);
            a0 += pe * f0.x; a1 += pe * f0.y;
            a2 += pe * f1.x; a3 += pe * f1.y;
        }
    }

    // reduce across the 4 edge subgroups (lane bits 4,5)
    a0 += __shfl_xor(a0, 16, 64); a0 += __shfl_xor(a0, 32, 64);
    a1 += __shfl_xor(a1, 16, 64); a1 += __shfl_xor(a1, 32, 64);
    a2 += __shfl_xor(a2, 16, 64); a2 += __shfl_xor(a2, 32, 64);
    a3 += __shfl_xor(a3, 16, 64); a3 += __shfl_xor(a3, 32, 64);
    float l = lane63_bcast(wave_sum_to63(l_lane));
    if (grp == 0) {
        float inv = 1.f / (l + 1e-16f);
        float4 b4 = ((const float4*)bias)[q];
        float o0 = a0 * inv + b4.x;
        float o1 = a1 * inv + b4.y;
        float o2 = a2 * inv + b4.z;
        float o3 = a3 * inv + b4.w;
        o0 = o0 > 0.f ? o0 : expm1f(o0);
        o1 = o1 > 0.f ? o1 : expm1f(o1);
        o2 = o2 > 0.f ? o2 : expm1f(o2);
        o3 = o3 > 0.f ? o3 : expm1f(o3);
        ((float4*)out)[d * 16 + q] = float4{o0, o1, o2, o3};
    }
}

// ---------------- fused pool + head: one block per graph ----------------
__global__ __launch_bounds__(256) void pool_head_kernel(
        const float* __restrict__ h, const int* __restrict__ batch,
        const float* __restrict__ fc1w, const float* __restrict__ fc1b,
        const float* __restrict__ fc2w, const float* __restrict__ fc2b,
        float* __restrict__ out) {
    int g = blockIdx.x;
    int lo = 0, hi = N_NODES;
    while (lo < hi) { int mid = (lo + hi) >> 1; if (batch[mid] < g) lo = mid + 1; else hi = mid; }
    int start = lo;
    hi = N_NODES;
    while (lo < hi) { int mid = (lo + hi) >> 1; if (batch[mid] < g + 1) lo = mid + 1; else hi = mid; }
    int end = lo;

    int lane = threadIdx.x & 63;
    int w = threadIdx.x >> 6;
    float s = 0.f;
    for (int n = start + w; n < end; n += 4) s += h[n * H + lane];
    __shared__ float red[4][H];
    __shared__ float gv[H];
    __shared__ float f[FC];
    __shared__ float lg[NC];
    red[w][lane] = s;
    __syncthreads();
    if (w == 0) {
        float tot = red[0][lane] + red[1][lane] + red[2][lane] + red[3][lane];
        gv[lane] = tot / fmaxf((float)(end - start), 1.f);
    }
    __syncthreads();
    int t = threadIdx.x;
    if (t < FC) {
        float acc = fc1b[t];
#pragma unroll 16
        for (int k = 0; k < H; ++k) acc += gv[k] * fc1w[k * FC + t];
        f[t] = fmaxf(acc, 0.f);
    }
    __syncthreads();
    if (t < NC) {
        float a = fc2b[t];
        for (int k = 0; k < FC; ++k) a += f[k] * fc2w[k * NC + t];
        lg[t] = a;
    }
    __syncthreads();
    if (t < NC) {
        float mx = fmaxf(lg[0], lg[1]);
        float lse = mx + logf(expf(lg[0] - mx) + expf(lg[1] - mx));
        out[g * NC + t] = lg[t] - lse;
    }
}

extern "C" void kernel_launch(void* const* d_in, const int* in_sizes, int n_in,
                              void* d_out, int out_size, void* d_ws, size_t ws_size,
                              hipStream_t stream) {
    const float* x         = (const float*)d_in[0];
    const int*   edge_idx  = (const int*)d_in[1];
    const float* edge_attr = (const float*)d_in[2];
    const int*   batch     = (const int*)d_in[3];
    const float* Wl0  = (const float*)d_in[4];
    const float* bl0  = (const float*)d_in[5];
    const float* Wr0  = (const float*)d_in[6];
    const float* br0  = (const float*)d_in[7];
    const float* We0  = (const float*)d_in[8];
    const float* att0 = (const float*)d_in[9];
    const float* bias0= (const float*)d_in[10];
    const float* Wl1  = (const float*)d_in[11];
    const float* bl1  = (const float*)d_in[12];
    const float* Wr1  = (const float*)d_in[13];
    const float* br1  = (const float*)d_in[14];
    const float* We1  = (const float*)d_in[15];
    const float* att1 = (const float*)d_in[16];
    const float* bias1= (const float*)d_in[17];
    const float* fc1w = (const float*)d_in[18];
    const float* fc1b = (const float*)d_in[19];
    const float* fc2w = (const float*)d_in[20];
    const float* fc2b = (const float*)d_in[21];

    // ---- workspace layout ----
    // tmp aliases [C | escore | pad] (tmp dead after fine_sort; C/escore written after).
    __half2* xlh    = (__half2*)d_ws;                 // [N*32]
    __half2* xrh    = xlh + N_NODES * 32;             // [N*32]
    float* C        = (float*)(xrh + N_NODES * 32);   // [N,64] fp32 ┐
    float* escore   = C + N_NODES * 64;               // [E]         ├ tmp aliases these
    float* pad      = escore + N_EDGES;               // [E]         ┘
    int4*  tmp      = (int4*)C;                       // [E]
    int4*  csr      = (int4*)(pad + N_EDGES);         // [E]
    int*   srcs     = (int*)(csr + N_EDGES);          // [E]
    int*   row_start= srcs + N_EDGES;                 // [N+1]
    int*   rank1    = row_start + N_NODES + 1;        // [E]
    int*   bhist    = rank1 + N_EDGES;                // [NB1*NBUCK]
    int*   bases    = bhist + NB1 * NBUCK;            // [NB1*NBUCK]
    int*   btot     = bases + NB1 * NBUCK;            // [NBUCK]
    int*   cb_start = btot + NBUCK;                   // [NBUCK+1]
    __half2* weh0   = (__half2*)(cb_start + NBUCK + 1);
    __half2* weh1   = weh0 + 128;
    __half2* wt1    = weh1 + 128;                     // [128*32]
    float* bb1      = (float*)(wt1 + 128 * 32);       // [128]
    __half2* atth0  = (__half2*)(bb1 + 128);          // [32]
    __half2* atth1  = atth0 + 32;                     // [32]

    const int* src = edge_idx;
    const int* dst = edge_idx + N_EDGES;

    const int edgeBlocks  = (N_EDGES + 255) / 256;
    const int scoreBlocks = N_EDGES / 64;             // 25000 (4 lanes/edge)
    const int waveBlocks  = (N_NODES * 64 + 255) / 256;
    const int p1Blocks    = (N_NODES + 63) / 64;
    const int frontBlocks = NB1 + PAIR_BLOCKS + 1;

    // ---- CSR build via 2-pass radix (LDS atomics, parallel scans) + proj0 + prep ----
    front_kernel<<<frontBlocks, 256, 0, stream>>>(dst, rank1, bhist,
                                                  x, Wl0, bl0, Wr0, br0, xlh, xrh,
                                                  We0, We1, Wl1, bl1, Wr1, br1,
                                                  weh0, weh1, wt1, bb1,
                                                  att0, att1, atth0, atth1);
    scan_a_kernel<<<NBUCK, 256, 0, stream>>>(bhist, bases, btot);
    scan_b_kernel<<<1, 1024, 0, stream>>>(btot, cb_start);
    coarse_scatter_kernel<<<edgeBlocks, 256, 0, stream>>>(src, dst, rank1, bases, cb_start,
                                                          edge_attr, tmp);
    fine_sort_kernel<<<NBUCK, 256, 0, stream>>>(cb_start, tmp, csr, srcs, row_start);

    // ---- layer 0 ----
    score_kernel<<<scoreBlocks, 256, 0, stream>>>(csr, xlh, xrh, weh0, atth0, escore);
    agg_kernel<<<waveBlocks, 256, 0, stream>>>(row_start, srcs, escore, xlh, bias0, C);

    // ---- layer 1 ----
    proj1_kernel<<<p1Blocks, 256, 0, stream>>>(C, wt1, bb1, xlh, xrh);
    score_kernel<<<scoreBlocks, 256, 0, stream>>>(csr, xlh, xrh, weh1, atth1, escore);
    agg_kernel<<<waveBlocks, 256, 0, stream>>>(row_start, srcs, escore, xlh, bias1, C);

    // ---- pool + head (fused) ----
    pool_head_kernel<<<G_GRAPHS, 256, 0, stream>>>(C, batch, fc1w, fc1b, fc2w, fc2b, (float*)d_out);
}